// Round 1
// baseline (905.770 us; speedup 1.0000x reference)
//
#include <hip/hip_runtime.h>
#include <hip/hip_bf16.h>
#include <stdint.h>

// Problem constants
// N=8192, C1=512, C2=128, M=4, B=256, TOPK=40, R=B*M*M=4096
#define EPSF 1e-5f

// ---------------- RNG variant switches (JAX threefry) ----------------
// Modern JAX defaults: jax_threefry_partitionable = True.
#define RNG_PARTITIONABLE 1
// For 32-bit random bits in partitionable mode JAX returns the second output
// word (bits2). Flip to 0 to use bits1 if output0 mismatches.
#define RNG_BITS_SECOND 1

__device__ __forceinline__ void threefry2x32(uint32_t k0, uint32_t k1,
                                             uint32_t c0, uint32_t c1,
                                             uint32_t& o0, uint32_t& o1) {
  const uint32_t ks2 = k0 ^ k1 ^ 0x1BD11BDAu;
  uint32_t x0 = c0 + k0, x1 = c1 + k1;
#define TFR(r) { x0 += x1; x1 = (x1 << (r)) | (x1 >> (32 - (r))); x1 ^= x0; }
  TFR(13) TFR(15) TFR(26) TFR(6)
  x0 += k1;  x1 += ks2 + 1u;
  TFR(17) TFR(29) TFR(16) TFR(24)
  x0 += ks2; x1 += k0 + 2u;
  TFR(13) TFR(15) TFR(26) TFR(6)
  x0 += k0;  x1 += k1 + 3u;
  TFR(17) TFR(29) TFR(16) TFR(24)
  x0 += k1;  x1 += ks2 + 4u;
  TFR(13) TFR(15) TFR(26) TFR(6)
  x0 += ks2; x1 += k0 + 5u;
#undef TFR
  o0 = x0; o1 = x1;
}

__device__ __forceinline__ void bitonic_sort8192(unsigned long long* lds, int t, int NT) {
  for (unsigned k = 2; k <= 8192u; k <<= 1) {
    for (unsigned j = k >> 1; j > 0; j >>= 1) {
      for (unsigned i = (unsigned)t; i < 8192u; i += (unsigned)NT) {
        unsigned l = i ^ j;
        if (l > i) {
          unsigned long long a = lds[i], b = lds[l];
          const bool up = ((i & k) == 0u);
          if ((a > b) == up) { lds[i] = b; lds[l] = a; }
        }
      }
      __syncthreads();
    }
  }
}

// One block per seed s in {0..3}. Reproduces
// jax.random.permutation(jax.random.key(s), 8192) (2-round sort shuffle),
// writes invperm[s][value] = position.
__global__ void perm_kernel(int* __restrict__ invperm) {
  extern __shared__ unsigned long long lds[];
  const int s = blockIdx.x, t = threadIdx.x, NT = blockDim.x;
  const uint32_t K0 = 0u, K1 = (uint32_t)s;
  uint32_t k1a, k1b, s1a, s1b, s2a, s2b, t0, t1;
#if RNG_PARTITIONABLE
  threefry2x32(K0, K1, 0u, 0u, k1a, k1b);   // key1   = enc(0,0)
  threefry2x32(K0, K1, 0u, 1u, s1a, s1b);   // subkey1= enc(0,1)
  threefry2x32(k1a, k1b, 0u, 1u, s2a, s2b); // subkey2
#else
  uint32_t a0, b0, a1, b1;
  threefry2x32(K0, K1, 0u, 2u, a0, b0);
  threefry2x32(K0, K1, 1u, 3u, a1, b1);
  k1a = a0; k1b = a1; s1a = b0; s1b = b1;
  threefry2x32(k1a, k1b, 0u, 2u, a0, b0);
  threefry2x32(k1a, k1b, 1u, 3u, a1, b1);
  s2a = b0; s2b = b1;
#endif
  // round 1: keys = bits1[i], values = i  -> composite (bits<<13)|i
  for (int i = t; i < 8192; i += NT) {
    uint32_t bits;
#if RNG_PARTITIONABLE
    threefry2x32(s1a, s1b, 0u, (uint32_t)i, t0, t1);
    bits = RNG_BITS_SECOND ? t1 : t0;
#else
    if (i < 4096) { threefry2x32(s1a, s1b, (uint32_t)i, (uint32_t)(i + 4096), t0, t1); bits = t0; }
    else          { threefry2x32(s1a, s1b, (uint32_t)(i - 4096), (uint32_t)i, t0, t1); bits = t1; }
#endif
    lds[i] = ((unsigned long long)bits << 13) | (unsigned long long)i;
  }
  __syncthreads();
  bitonic_sort8192(lds, t, NT);
  // round 2: new keys at each position, carry values
  for (int i = t; i < 8192; i += NT) {
    unsigned long long val = lds[i] & 8191ull;
    uint32_t bits;
#if RNG_PARTITIONABLE
    threefry2x32(s2a, s2b, 0u, (uint32_t)i, t0, t1);
    bits = RNG_BITS_SECOND ? t1 : t0;
#else
    if (i < 4096) { threefry2x32(s2a, s2b, (uint32_t)i, (uint32_t)(i + 4096), t0, t1); bits = t0; }
    else          { threefry2x32(s2a, s2b, (uint32_t)(i - 4096), (uint32_t)i, t0, t1); bits = t1; }
#endif
    lds[i] = ((unsigned long long)bits << 26) |
             ((unsigned long long)(unsigned)i << 13) | val;
  }
  __syncthreads();
  bitonic_sort8192(lds, t, NT);
  for (int i = t; i < 8192; i += NT) {
    int val = (int)(lds[i] & 8191ull);
    invperm[s * 8192 + val] = i;
  }
}

// q_raw[r][c] = x_chunk[r>>2] . Wq_row[(r&3)*128+c] + bq   (r = cr*4 + m2)
__global__ __launch_bounds__(256) void qraw_kernel(const float* __restrict__ x,
    const float* __restrict__ Wq, const float* __restrict__ bq,
    float* __restrict__ qraw) {
  __shared__ float ea[16][128];
  __shared__ float wq[128][132];
  const int t = threadIdx.x;
  const int g = blockIdx.x;    // 0..63 : 16 consecutive x-chunks
  const int m2 = blockIdx.y;   // 0..3
  for (int i = t; i < 512; i += 256) {
    float4 xx = *(const float4*)(x + (size_t)g * 2048 + i * 4);
    *(float4*)&ea[i >> 5][(i & 31) * 4] = xx;
  }
  for (int i = t; i < 4096; i += 256) {
    float4 ww = *(const float4*)(Wq + (size_t)m2 * 16384 + i * 4);
    *(float4*)&wq[i >> 5][(i & 31) * 4] = ww;
  }
  __syncthreads();
  const int row = t >> 4, j = t & 15;
  float acc[8] = {0.f,0.f,0.f,0.f,0.f,0.f,0.f,0.f};
  for (int d = 0; d < 128; d++) {
    const float xv = ea[row][d];
#pragma unroll
    for (int cc = 0; cc < 8; cc++) acc[cc] += xv * wq[j + cc * 16][d];
  }
  const int r = (g * 16 + row) * 4 + m2;
#pragma unroll
  for (int cc = 0; cc < 8; cc++) {
    const int c = j + cc * 16;
    qraw[(size_t)r * 128 + c] = acc[cc] + bq[m2 * 128 + c];
  }
}

__global__ __launch_bounds__(256) void bnpart_kernel(const float* __restrict__ qraw,
                                                     float* __restrict__ bnpart) {
  __shared__ float a1[256], a2[256];
  const int t = threadIdx.x, c = t & 127, h = t >> 7;
  float s1 = 0.f, s2 = 0.f;
  for (int i = 0; i < 64; i++) {
    float xv = qraw[(size_t)(blockIdx.x * 128 + h + 2 * i) * 128 + c];
    s1 += xv; s2 += xv * xv;
  }
  a1[t] = s1; a2[t] = s2;
  __syncthreads();
  if (t < 128) {
    bnpart[blockIdx.x * 256 + t]       = a1[t] + a1[t + 128];
    bnpart[blockIdx.x * 256 + 128 + t] = a2[t] + a2[t + 128];
  }
}

__global__ void bnfin_kernel(const float* __restrict__ bnpart,
                             const float* __restrict__ gamma,
                             const float* __restrict__ beta,
                             float* __restrict__ bnstat) {
  const int c = threadIdx.x;  // 128 threads
  float s1 = 0.f, s2 = 0.f;
  for (int i = 0; i < 32; i++) { s1 += bnpart[i * 256 + c]; s2 += bnpart[i * 256 + 128 + c]; }
  const float mu  = s1 * (1.0f / 4096.0f);
  const float var = s2 * (1.0f / 4096.0f) - mu * mu;
  const float sc  = rsqrtf(var + EPSF) * gamma[c];
  bnstat[c]       = sc;
  bnstat[128 + c] = beta[c] - mu * sc;
}

__global__ __launch_bounds__(256) void qnorm_kernel(const float* __restrict__ qraw,
    const float* __restrict__ bnstat, float* __restrict__ outq) {
  const int idx4 = blockIdx.x * 256 + threadIdx.x;  // 0..131071
  float4 xv = *(const float4*)(qraw + (size_t)idx4 * 4);
  const int c0 = (idx4 * 4) & 127;
  float4 sc = *(const float4*)(bnstat + c0);
  float4 sh = *(const float4*)(bnstat + 128 + c0);
  float4 o;
  o.x = xv.x * sc.x + sh.x; o.y = xv.y * sc.y + sh.y;
  o.z = xv.z * sc.z + sh.z; o.w = xv.w * sc.w + sh.w;
  *(float4*)(outq + (size_t)idx4 * 4) = o;
}

// LN(embedding) -> kbuf (flat [8192][128] == reshaped [128][8192]); v = emb@Wv^T+bv
__global__ __launch_bounds__(256) void lnv_kernel(const float* __restrict__ emb,
    const float* __restrict__ Wv, const float* __restrict__ bv,
    const float* __restrict__ lng, const float* __restrict__ lnb,
    float* __restrict__ kbuf, float* __restrict__ vbuf) {
  __shared__ float ea[16][128];
  __shared__ float wv[128][132];
  const int t = threadIdx.x;
  const int r0 = blockIdx.x * 16;
  for (int i = t; i < 512; i += 256) {
    float4 xx = *(const float4*)(emb + (size_t)r0 * 128 + i * 4);
    *(float4*)&ea[i >> 5][(i & 31) * 4] = xx;
  }
  for (int i = t; i < 4096; i += 256) {
    float4 ww = *(const float4*)(Wv + (size_t)i * 4);
    *(float4*)&wv[i >> 5][(i & 31) * 4] = ww;
  }
  __syncthreads();
  const int row = t >> 4, j = t & 15;
  float s1 = 0.f, s2 = 0.f;
#pragma unroll
  for (int m = 0; m < 8; m++) { float xv = ea[row][j + m * 16]; s1 += xv; s2 += xv * xv; }
#pragma unroll
  for (int off = 8; off; off >>= 1) {
    s1 += __shfl_xor(s1, off, 16);
    s2 += __shfl_xor(s2, off, 16);
  }
  const float mu   = s1 * 0.0078125f;
  const float var  = s2 * 0.0078125f - mu * mu;
  const float rstd = rsqrtf(var + EPSF);
#pragma unroll
  for (int m = 0; m < 8; m++) {
    const int d = j + m * 16;
    kbuf[(size_t)(r0 + row) * 128 + d] = (ea[row][d] - mu) * rstd * lng[d] + lnb[d];
  }
  float acc[8] = {0.f,0.f,0.f,0.f,0.f,0.f,0.f,0.f};
  for (int d = 0; d < 128; d++) {
    const float xv = ea[row][d];
#pragma unroll
    for (int cc = 0; cc < 8; cc++) acc[cc] += xv * wv[j + cc * 16][d];
  }
#pragma unroll
  for (int cc = 0; cc < 8; cc++) {
    const int c = j + cc * 16;
    vbuf[(size_t)(r0 + row) * 128 + c] = acc[cc] + bv[c];
  }
}

// logits[4096][8192] = (q[4096][128] @ k[128][8192]) / sqrt(128)
__global__ __launch_bounds__(256) void gemm1_kernel(const float* __restrict__ qm,
    const float* __restrict__ km, float* __restrict__ logits) {
  __shared__ float As[32][132];
  __shared__ float Bs[32][132];
  const int t = threadIdx.x;
  const int n0 = blockIdx.x * 128;
  const int r0 = blockIdx.y * 128;
  const int tx = t & 15, ty = t >> 4;
  const int ar = t >> 1, ak = (t & 1) * 16;
  const int bk = t >> 3, bc = (t & 7) * 16;
  float acc[8][8];
#pragma unroll
  for (int i = 0; i < 8; i++)
#pragma unroll
    for (int j = 0; j < 8; j++) acc[i][j] = 0.f;

  for (int kk = 0; kk < 128; kk += 32) {
    float4 av[4], bv4[4];
#pragma unroll
    for (int i = 0; i < 4; i++)
      av[i] = *(const float4*)(qm + (size_t)(r0 + ar) * 128 + kk + ak + i * 4);
#pragma unroll
    for (int i = 0; i < 4; i++)
      bv4[i] = *(const float4*)(km + (size_t)(kk + bk) * 8192 + n0 + bc + i * 4);
    __syncthreads();
#pragma unroll
    for (int i = 0; i < 4; i++) {
      As[ak + i * 4 + 0][ar] = av[i].x;
      As[ak + i * 4 + 1][ar] = av[i].y;
      As[ak + i * 4 + 2][ar] = av[i].z;
      As[ak + i * 4 + 3][ar] = av[i].w;
      *(float4*)&Bs[bk][bc + i * 4] = bv4[i];
    }
    __syncthreads();
#pragma unroll
    for (int k = 0; k < 32; k++) {
      float4 a0 = *(const float4*)&As[k][ty * 4];
      float4 a1 = *(const float4*)&As[k][64 + ty * 4];
      float4 b0 = *(const float4*)&Bs[k][tx * 4];
      float4 b1 = *(const float4*)&Bs[k][64 + tx * 4];
      float aa[8] = {a0.x,a0.y,a0.z,a0.w,a1.x,a1.y,a1.z,a1.w};
      float bb[8] = {b0.x,b0.y,b0.z,b0.w,b1.x,b1.y,b1.z,b1.w};
#pragma unroll
      for (int i = 0; i < 8; i++)
#pragma unroll
        for (int jj = 0; jj < 8; jj++)
          acc[i][jj] = fmaf(aa[i], bb[jj], acc[i][jj]);
    }
  }
  const float rs = 0.08838834764831845f;  // 1/sqrt(128)
#pragma unroll
  for (int i = 0; i < 8; i++) {
    const int r = r0 + ((i < 4) ? (ty * 4 + i) : (64 + ty * 4 + i - 4));
    float4 o0, o1;
    o0.x = acc[i][0] * rs; o0.y = acc[i][1] * rs; o0.z = acc[i][2] * rs; o0.w = acc[i][3] * rs;
    o1.x = acc[i][4] * rs; o1.y = acc[i][5] * rs; o1.z = acc[i][6] * rs; o1.w = acc[i][7] * rs;
    *(float4*)(logits + (size_t)r * 8192 + n0 + tx * 4) = o0;
    *(float4*)(logits + (size_t)r * 8192 + n0 + 64 + tx * 4) = o1;
  }
}

// Per row: max, sum(exp), then top-40 (value desc, tie -> lower index)
__global__ __launch_bounds__(256) void rowstat_topk_kernel(const float* __restrict__ logits,
    float* __restrict__ rowmax, float* __restrict__ rowsum,
    float* __restrict__ topv, int* __restrict__ topi) {
  const int r = blockIdx.x, t = threadIdx.x;
  const int lane = t & 63, wave = t >> 6;
  const float* row = logits + (size_t)r * 8192;
  float4 v[8];
#pragma unroll
  for (int m = 0; m < 8; m++) v[m] = *(const float4*)(row + m * 1024 + t * 4);

  __shared__ float redf[4];
  __shared__ float wvs[4];
  __shared__ int wis[4];

  float lv = -3.0e38f; int li = 0;
#pragma unroll
  for (int m = 0; m < 8; m++) {
    const int gb = m * 1024 + t * 4;
    if (v[m].x > lv) { lv = v[m].x; li = gb; }
    if (v[m].y > lv) { lv = v[m].y; li = gb + 1; }
    if (v[m].z > lv) { lv = v[m].z; li = gb + 2; }
    if (v[m].w > lv) { lv = v[m].w; li = gb + 3; }
  }
  float bm = lv;
#pragma unroll
  for (int off = 32; off; off >>= 1) bm = fmaxf(bm, __shfl_xor(bm, off));
  if (lane == 0) redf[wave] = bm;
  __syncthreads();
  const float gmax = fmaxf(fmaxf(redf[0], redf[1]), fmaxf(redf[2], redf[3]));
  float ls = 0.f;
#pragma unroll
  for (int m = 0; m < 8; m++)
    ls += expf(v[m].x - gmax) + expf(v[m].y - gmax) + expf(v[m].z - gmax) + expf(v[m].w - gmax);
#pragma unroll
  for (int off = 32; off; off >>= 1) ls += __shfl_xor(ls, off);
  __syncthreads();
  if (lane == 0) redf[wave] = ls;
  __syncthreads();
  const float gsum = redf[0] + redf[1] + redf[2] + redf[3];
  if (t == 0) { rowmax[r] = gmax; rowsum[r] = gsum; }

  unsigned mask = 0u;
  for (int it = 0; it < 40; ++it) {
    float cv = lv; int ci = li;
#pragma unroll
    for (int off = 32; off; off >>= 1) {
      const float ov = __shfl_xor(cv, off);
      const int oi = __shfl_xor(ci, off);
      if (ov > cv || (ov == cv && oi < ci)) { cv = ov; ci = oi; }
    }
    if (lane == 0) { wvs[wave] = cv; wis[wave] = ci; }
    __syncthreads();
    float wv = wvs[0]; int wi = wis[0];
#pragma unroll
    for (int w = 1; w < 4; w++)
      if (wvs[w] > wv || (wvs[w] == wv && wis[w] < wi)) { wv = wvs[w]; wi = wis[w]; }
    if (t == 0) { topi[r * 40 + it] = wi; topv[r * 40 + it] = expf(wv - gmax) / gsum; }
    if (((wi >> 2) & 255) == t) {
      mask |= 1u << (((wi >> 10) << 2) | (wi & 3));
      lv = -3.0e38f; li = 0;
#pragma unroll
      for (int m = 0; m < 8; m++) {
        const int gb = m * 1024 + t * 4;
        if (!(mask & (1u << (m * 4 + 0))) && v[m].x > lv) { lv = v[m].x; li = gb; }
        if (!(mask & (1u << (m * 4 + 1))) && v[m].y > lv) { lv = v[m].y; li = gb + 1; }
        if (!(mask & (1u << (m * 4 + 2))) && v[m].z > lv) { lv = v[m].z; li = gb + 2; }
        if (!(mask & (1u << (m * 4 + 3))) && v[m].w > lv) { lv = v[m].w; li = gb + 3; }
      }
    }
    __syncthreads();
  }
}

// partial PV: pvpart[kchunk][4096][128]; P computed on the fly from logits
__global__ __launch_bounds__(256) void gemm2_kernel(const float* __restrict__ logits,
    const float* __restrict__ vmat, const float* __restrict__ rowmax,
    const float* __restrict__ rowsum, float* __restrict__ pvpart) {
  __shared__ float Ps[32][132];
  __shared__ float Vs[32][132];
  const int t = threadIdx.x;
  const int bx = blockIdx.x;  // k-chunk 0..15 (512 wide)
  const int by = blockIdx.y;  // row block 0..31
  const int r0 = by * 128;
  const int kbase = bx * 512;
  const int tx = t & 15, ty = t >> 4;
  const int ar = t >> 1, ak = (t & 1) * 16;
  const int bk = t >> 3, bc = (t & 7) * 16;
  const float rm = rowmax[r0 + ar];
  const float ri = 1.0f / rowsum[r0 + ar];
  float acc[8][8];
#pragma unroll
  for (int i = 0; i < 8; i++)
#pragma unroll
    for (int j = 0; j < 8; j++) acc[i][j] = 0.f;

  for (int kk = 0; kk < 512; kk += 32) {
    float4 av[4], bv4[4];
#pragma unroll
    for (int i = 0; i < 4; i++)
      av[i] = *(const float4*)(logits + (size_t)(r0 + ar) * 8192 + kbase + kk + ak + i * 4);
#pragma unroll
    for (int i = 0; i < 4; i++)
      bv4[i] = *(const float4*)(vmat + (size_t)(kbase + kk + bk) * 128 + bc + i * 4);
    __syncthreads();
#pragma unroll
    for (int i = 0; i < 4; i++) {
      Ps[ak + i * 4 + 0][ar] = expf(av[i].x - rm) * ri;
      Ps[ak + i * 4 + 1][ar] = expf(av[i].y - rm) * ri;
      Ps[ak + i * 4 + 2][ar] = expf(av[i].z - rm) * ri;
      Ps[ak + i * 4 + 3][ar] = expf(av[i].w - rm) * ri;
      *(float4*)&Vs[bk][bc + i * 4] = bv4[i];
    }
    __syncthreads();
#pragma unroll
    for (int k = 0; k < 32; k++) {
      float4 a0 = *(const float4*)&Ps[k][ty * 4];
      float4 a1 = *(const float4*)&Ps[k][64 + ty * 4];
      float4 b0 = *(const float4*)&Vs[k][tx * 4];
      float4 b1 = *(const float4*)&Vs[k][64 + tx * 4];
      float aa[8] = {a0.x,a0.y,a0.z,a0.w,a1.x,a1.y,a1.z,a1.w};
      float bb[8] = {b0.x,b0.y,b0.z,b0.w,b1.x,b1.y,b1.z,b1.w};
#pragma unroll
      for (int i = 0; i < 8; i++)
#pragma unroll
        for (int jj = 0; jj < 8; jj++)
          acc[i][jj] = fmaf(aa[i], bb[jj], acc[i][jj]);
    }
  }
#pragma unroll
  for (int i = 0; i < 8; i++) {
    const int r = r0 + ((i < 4) ? (ty * 4 + i) : (64 + ty * 4 + i - 4));
    float4 o0, o1;
    o0.x = acc[i][0]; o0.y = acc[i][1]; o0.z = acc[i][2]; o0.w = acc[i][3];
    o1.x = acc[i][4]; o1.y = acc[i][5]; o1.z = acc[i][6]; o1.w = acc[i][7];
    *(float4*)(pvpart + ((size_t)bx * 4096 + r) * 128 + tx * 4) = o0;
    *(float4*)(pvpart + ((size_t)bx * 4096 + r) * 128 + 64 + tx * 4) = o1;
  }
}

__global__ __launch_bounds__(256) void pvred_kernel(const float* __restrict__ pvpart,
    float* __restrict__ o2, float* __restrict__ o3) {
  const int idx4 = blockIdx.x * 256 + threadIdx.x;  // 0..131071
  float4 s; s.x = s.y = s.z = s.w = 0.f;
#pragma unroll
  for (int ch = 0; ch < 16; ch++) {
    float4 p = *(const float4*)(pvpart + (size_t)ch * 524288 + (size_t)idx4 * 4);
    s.x += p.x; s.y += p.y; s.z += p.z; s.w += p.w;
  }
  *(float4*)(o2 + (size_t)idx4 * 4) = s;
  *(float4*)(o3 + (size_t)idx4 * 4) = s;
}

__global__ __launch_bounds__(256) void seedscatter_kernel(const int* __restrict__ topi,
    const float* __restrict__ topv, const int* __restrict__ invperm,
    float* __restrict__ out0) {
  const int b = blockIdx.x, t = threadIdx.x;
  int s = 0;
  for (int e = t; e < 640; e += 256) s += topi[b * 640 + e];
#pragma unroll
  for (int off = 32; off; off >>= 1) s += __shfl_xor(s, off);
  __shared__ int sred[4];
  if ((t & 63) == 0) sred[t >> 6] = s;
  __syncthreads();
  const int total = sred[0] + sred[1] + sred[2] + sred[3];
  const float avg = (float)total / 640.0f;
  const int sd = ((int)floorf(avg / 2048.0f)) & 3;
  const int* ip = invperm + sd * 8192;
  for (int e = t; e < 640; e += 256) {
    const int q = e / 40;
    const int i = topi[b * 640 + e];
    const float val = topv[b * 640 + e];
    out0[((size_t)(b * 16 + q)) * 8192 + ip[i]] = val;
  }
}

extern "C" void kernel_launch(void* const* d_in, const int* in_sizes, int n_in,
                              void* d_out, int out_size, void* d_ws, size_t ws_size,
                              hipStream_t stream) {
  const float* x   = (const float*)d_in[0];
  const float* emb = (const float*)d_in[1];
  const float* Wq  = (const float*)d_in[2];
  const float* bq  = (const float*)d_in[3];
  const float* Wv  = (const float*)d_in[4];
  const float* bv  = (const float*)d_in[5];
  const float* bng = (const float*)d_in[6];
  const float* bnb = (const float*)d_in[7];
  const float* lng = (const float*)d_in[8];
  const float* lnb = (const float*)d_in[9];

  float* out0  = (float*)d_out;          // attn_w_flat [4096*8192] (also logits scratch)
  float* outq  = out0 + 33554432;        // q [4096*128]
  float* outap = outq + 524288;          // applied
  float* outaf = outap + 524288;         // applied_flat

  float* wsf    = (float*)d_ws;
  float* kbuf   = wsf;                   // 1048576
  float* vbuf   = kbuf + 1048576;        // 1048576
  float* qraw   = vbuf + 1048576;        // 524288
  float* bnpart = qraw + 524288;         // 8192
  float* bnstat = bnpart + 8192;         // 256
  float* rowmax = bnstat + 256;          // 4096
  float* rowsum = rowmax + 4096;         // 4096
  float* pvpart = rowsum + 4096;         // 16*4096*128 = 8388608
  float* topv   = pvpart + 8388608;      // 163840
  int*   topi    = (int*)(topv + 163840);  // 163840
  int*   invperm = topi + 163840;          // 4*8192

  perm_kernel<<<4, 1024, 65536, stream>>>(invperm);
  qraw_kernel<<<dim3(64, 4), 256, 0, stream>>>(x, Wq, bq, qraw);
  bnpart_kernel<<<32, 256, 0, stream>>>(qraw, bnpart);
  bnfin_kernel<<<1, 128, 0, stream>>>(bnpart, bng, bnb, bnstat);
  qnorm_kernel<<<512, 256, 0, stream>>>(qraw, bnstat, outq);
  lnv_kernel<<<512, 256, 0, stream>>>(emb, Wv, bv, lng, lnb, kbuf, vbuf);
  gemm1_kernel<<<dim3(64, 32), 256, 0, stream>>>(outq, kbuf, out0);
  rowstat_topk_kernel<<<4096, 256, 0, stream>>>(out0, rowmax, rowsum, topv, topi);
  gemm2_kernel<<<dim3(16, 32), 256, 0, stream>>>(out0, vbuf, rowmax, rowsum, pvpart);
  pvred_kernel<<<512, 256, 0, stream>>>(pvpart, outap, outaf);
  hipMemsetAsync(d_out, 0, (size_t)33554432 * 4, stream);
  seedscatter_kernel<<<256, 256, 0, stream>>>(topi, topv, invperm, out0);
}

// Round 2
// 814.209 us; speedup vs baseline: 1.1125x; 1.1125x over previous
//
#include <hip/hip_runtime.h>
#include <hip/hip_bf16.h>
#include <stdint.h>

// N=8192, C1=512, C2=128, M=4, B=256, TOPK=40, R=B*M*M=4096
#define EPSF 1e-5f

typedef __bf16 b16x8 __attribute__((ext_vector_type(8)));
typedef float f32x4 __attribute__((ext_vector_type(4)));
typedef unsigned short u16x8 __attribute__((ext_vector_type(8)));

static __device__ __forceinline__ unsigned short f2bf(float f) {
  __hip_bfloat16 h = __float2bfloat16(f);
  return __builtin_bit_cast(unsigned short, h);
}

// ---------------- RNG (JAX threefry, partitionable) ----------------
#define RNG_PARTITIONABLE 1
#define RNG_BITS_SECOND 1

__device__ __forceinline__ void threefry2x32(uint32_t k0, uint32_t k1,
                                             uint32_t c0, uint32_t c1,
                                             uint32_t& o0, uint32_t& o1) {
  const uint32_t ks2 = k0 ^ k1 ^ 0x1BD11BDAu;
  uint32_t x0 = c0 + k0, x1 = c1 + k1;
#define TFR(r) { x0 += x1; x1 = (x1 << (r)) | (x1 >> (32 - (r))); x1 ^= x0; }
  TFR(13) TFR(15) TFR(26) TFR(6)
  x0 += k1;  x1 += ks2 + 1u;
  TFR(17) TFR(29) TFR(16) TFR(24)
  x0 += ks2; x1 += k0 + 2u;
  TFR(13) TFR(15) TFR(26) TFR(6)
  x0 += k0;  x1 += k1 + 3u;
  TFR(17) TFR(29) TFR(16) TFR(24)
  x0 += k1;  x1 += ks2 + 4u;
  TFR(13) TFR(15) TFR(26) TFR(6)
  x0 += ks2; x1 += k0 + 5u;
#undef TFR
  o0 = x0; o1 = x1;
}

__device__ __forceinline__ void bitonic_sort8192(unsigned long long* lds, int t, int NT) {
  for (unsigned k = 2; k <= 8192u; k <<= 1) {
    for (unsigned j = k >> 1; j > 0; j >>= 1) {
      for (unsigned i = (unsigned)t; i < 8192u; i += (unsigned)NT) {
        unsigned l = i ^ j;
        if (l > i) {
          unsigned long long a = lds[i], b = lds[l];
          const bool up = ((i & k) == 0u);
          if ((a > b) == up) { lds[i] = b; lds[l] = a; }
        }
      }
      __syncthreads();
    }
  }
}

__global__ void perm_kernel(int* __restrict__ invperm) {
  extern __shared__ unsigned long long lds[];
  const int s = blockIdx.x, t = threadIdx.x, NT = blockDim.x;
  const uint32_t K0 = 0u, K1 = (uint32_t)s;
  uint32_t k1a, k1b, s1a, s1b, s2a, s2b, t0, t1;
  threefry2x32(K0, K1, 0u, 0u, k1a, k1b);
  threefry2x32(K0, K1, 0u, 1u, s1a, s1b);
  threefry2x32(k1a, k1b, 0u, 1u, s2a, s2b);
  for (int i = t; i < 8192; i += NT) {
    uint32_t bits;
    threefry2x32(s1a, s1b, 0u, (uint32_t)i, t0, t1);
    bits = RNG_BITS_SECOND ? t1 : t0;
    lds[i] = ((unsigned long long)bits << 13) | (unsigned long long)i;
  }
  __syncthreads();
  bitonic_sort8192(lds, t, NT);
  for (int i = t; i < 8192; i += NT) {
    unsigned long long val = lds[i] & 8191ull;
    uint32_t bits;
    threefry2x32(s2a, s2b, 0u, (uint32_t)i, t0, t1);
    bits = RNG_BITS_SECOND ? t1 : t0;
    lds[i] = ((unsigned long long)bits << 26) |
             ((unsigned long long)(unsigned)i << 13) | val;
  }
  __syncthreads();
  bitonic_sort8192(lds, t, NT);
  for (int i = t; i < 8192; i += NT) {
    int val = (int)(lds[i] & 8191ull);
    invperm[s * 8192 + val] = i;
  }
}

// ---------------- q path ----------------
__global__ __launch_bounds__(256) void qraw_kernel(const float* __restrict__ x,
    const float* __restrict__ Wq, const float* __restrict__ bq,
    float* __restrict__ qraw) {
  __shared__ float ea[16][128];
  __shared__ float wq[128][132];
  const int t = threadIdx.x;
  const int g = blockIdx.x;
  const int m2 = blockIdx.y;
  for (int i = t; i < 512; i += 256) {
    float4 xx = *(const float4*)(x + (size_t)g * 2048 + i * 4);
    *(float4*)&ea[i >> 5][(i & 31) * 4] = xx;
  }
  for (int i = t; i < 4096; i += 256) {
    float4 ww = *(const float4*)(Wq + (size_t)m2 * 16384 + i * 4);
    *(float4*)&wq[i >> 5][(i & 31) * 4] = ww;
  }
  __syncthreads();
  const int row = t >> 4, j = t & 15;
  float acc[8] = {0.f,0.f,0.f,0.f,0.f,0.f,0.f,0.f};
  for (int d = 0; d < 128; d++) {
    const float xv = ea[row][d];
#pragma unroll
    for (int cc = 0; cc < 8; cc++) acc[cc] += xv * wq[j + cc * 16][d];
  }
  const int r = (g * 16 + row) * 4 + m2;
#pragma unroll
  for (int cc = 0; cc < 8; cc++) {
    const int c = j + cc * 16;
    qraw[(size_t)r * 128 + c] = acc[cc] + bq[m2 * 128 + c];
  }
}

__global__ __launch_bounds__(256) void bnpart_kernel(const float* __restrict__ qraw,
                                                     float* __restrict__ bnpart) {
  __shared__ float a1[256], a2[256];
  const int t = threadIdx.x, c = t & 127, h = t >> 7;
  float s1 = 0.f, s2 = 0.f;
  for (int i = 0; i < 64; i++) {
    float xv = qraw[(size_t)(blockIdx.x * 128 + h + 2 * i) * 128 + c];
    s1 += xv; s2 += xv * xv;
  }
  a1[t] = s1; a2[t] = s2;
  __syncthreads();
  if (t < 128) {
    bnpart[blockIdx.x * 256 + t]       = a1[t] + a1[t + 128];
    bnpart[blockIdx.x * 256 + 128 + t] = a2[t] + a2[t + 128];
  }
}

__global__ void bnfin_kernel(const float* __restrict__ bnpart,
                             const float* __restrict__ gamma,
                             const float* __restrict__ beta,
                             float* __restrict__ bnstat) {
  const int c = threadIdx.x;
  float s1 = 0.f, s2 = 0.f;
  for (int i = 0; i < 32; i++) { s1 += bnpart[i * 256 + c]; s2 += bnpart[i * 256 + 128 + c]; }
  const float mu  = s1 * (1.0f / 4096.0f);
  const float var = s2 * (1.0f / 4096.0f) - mu * mu;
  const float sc  = rsqrtf(var + EPSF) * gamma[c];
  bnstat[c]       = sc;
  bnstat[128 + c] = beta[c] - mu * sc;
}

__global__ __launch_bounds__(256) void qnorm_kernel(const float* __restrict__ qraw,
    const float* __restrict__ bnstat, float* __restrict__ outq,
    unsigned short* __restrict__ qb) {
  const int idx4 = blockIdx.x * 256 + threadIdx.x;
  float4 xv = *(const float4*)(qraw + (size_t)idx4 * 4);
  const int c0 = (idx4 * 4) & 127;
  float4 sc = *(const float4*)(bnstat + c0);
  float4 sh = *(const float4*)(bnstat + 128 + c0);
  float4 o;
  o.x = xv.x * sc.x + sh.x; o.y = xv.y * sc.y + sh.y;
  o.z = xv.z * sc.z + sh.z; o.w = xv.w * sc.w + sh.w;
  *(float4*)(outq + (size_t)idx4 * 4) = o;
  ushort4 ob;
  ob.x = f2bf(o.x); ob.y = f2bf(o.y); ob.z = f2bf(o.z); ob.w = f2bf(o.w);
  *(ushort4*)(qb + (size_t)idx4 * 4) = ob;
}

// ---------------- LN(emb) -> kbuf, emb@Wv^T+bv -> vbuf ----------------
__global__ __launch_bounds__(256) void lnv_kernel(const float* __restrict__ emb,
    const float* __restrict__ Wv, const float* __restrict__ bv,
    const float* __restrict__ lng, const float* __restrict__ lnb,
    float* __restrict__ kbuf, float* __restrict__ vbuf) {
  __shared__ float ea[16][128];
  __shared__ float wv[128][132];
  const int t = threadIdx.x;
  const int r0 = blockIdx.x * 16;
  for (int i = t; i < 512; i += 256) {
    float4 xx = *(const float4*)(emb + (size_t)r0 * 128 + i * 4);
    *(float4*)&ea[i >> 5][(i & 31) * 4] = xx;
  }
  for (int i = t; i < 4096; i += 256) {
    float4 ww = *(const float4*)(Wv + (size_t)i * 4);
    *(float4*)&wv[i >> 5][(i & 31) * 4] = ww;
  }
  __syncthreads();
  const int row = t >> 4, j = t & 15;
  float s1 = 0.f, s2 = 0.f;
#pragma unroll
  for (int m = 0; m < 8; m++) { float xv = ea[row][j + m * 16]; s1 += xv; s2 += xv * xv; }
#pragma unroll
  for (int off = 8; off; off >>= 1) {
    s1 += __shfl_xor(s1, off, 16);
    s2 += __shfl_xor(s2, off, 16);
  }
  const float mu   = s1 * 0.0078125f;
  const float var  = s2 * 0.0078125f - mu * mu;
  const float rstd = rsqrtf(var + EPSF);
#pragma unroll
  for (int m = 0; m < 8; m++) {
    const int d = j + m * 16;
    kbuf[(size_t)(r0 + row) * 128 + d] = (ea[row][d] - mu) * rstd * lng[d] + lnb[d];
  }
  float acc[8] = {0.f,0.f,0.f,0.f,0.f,0.f,0.f,0.f};
  for (int d = 0; d < 128; d++) {
    const float xv = ea[row][d];
#pragma unroll
    for (int cc = 0; cc < 8; cc++) acc[cc] += xv * wv[j + cc * 16][d];
  }
#pragma unroll
  for (int cc = 0; cc < 8; cc++) {
    const int c = j + cc * 16;
    vbuf[(size_t)(r0 + row) * 128 + c] = acc[cc] + bv[c];
  }
}

// ---------------- bf16 transposes for MFMA B-operands ----------------
// kT[n][k] = K_reshaped[k][n] = kbuf_flat[k*8192+n]; element (k, n0+dn) lives at
// kbuf[k*64 + (b>>1)][(b&1)*64 + dn]  (n0 = b*64).
__global__ __launch_bounds__(256) void ktrans_kernel(const float* __restrict__ kbuf,
                                                     unsigned short* __restrict__ kT) {
  __shared__ unsigned short s[64][136];
  const int b = blockIdx.x, t = threadIdx.x;
  const int k = t >> 1, half = t & 1;
  const float* src = kbuf + (size_t)(k * 64 + (b >> 1)) * 128 + (b & 1) * 64 + half * 32;
#pragma unroll
  for (int i = 0; i < 8; i++) {
    float4 v = *(const float4*)(src + i * 4);
    const int dn = half * 32 + i * 4;
    s[dn + 0][k] = f2bf(v.x); s[dn + 1][k] = f2bf(v.y);
    s[dn + 2][k] = f2bf(v.z); s[dn + 3][k] = f2bf(v.w);
  }
  __syncthreads();
  const int dn = t >> 2, q = t & 3;
  unsigned short* dst = kT + (size_t)(b * 64 + dn) * 128 + q * 32;
#pragma unroll
  for (int j = 0; j < 4; j++)
    *(int4*)(dst + j * 8) = *(const int4*)&s[dn][q * 32 + j * 8];
}

// vT[c][i] = vbuf[i][c]
__global__ __launch_bounds__(256) void vtrans_kernel(const float* __restrict__ vbuf,
                                                     unsigned short* __restrict__ vT) {
  __shared__ unsigned short s[128][72];
  const int b = blockIdx.x, t = threadIdx.x;
  const int i0 = b * 64;
  const int di = t >> 2, q = t & 3;
  const float* src = vbuf + (size_t)(i0 + di) * 128 + q * 32;
#pragma unroll
  for (int i = 0; i < 8; i++) {
    float4 v = *(const float4*)(src + i * 4);
    const int c = q * 32 + i * 4;
    s[c + 0][di] = f2bf(v.x); s[c + 1][di] = f2bf(v.y);
    s[c + 2][di] = f2bf(v.z); s[c + 3][di] = f2bf(v.w);
  }
  __syncthreads();
  const int c = t >> 1, half = t & 1;
  unsigned short* dst = vT + (size_t)c * 8192 + i0 + half * 32;
#pragma unroll
  for (int j = 0; j < 4; j++)
    *(int4*)(dst + j * 8) = *(const int4*)&s[c][half * 32 + j * 8];
}

// ---------------- GEMM1 (MFMA): logits[4096][8192] = qb @ kT^T / sqrt(128) ----------------
__global__ __launch_bounds__(256) void gemm1_mfma(const unsigned short* __restrict__ qb,
    const unsigned short* __restrict__ kT, float* __restrict__ logits) {
  __shared__ __attribute__((aligned(16))) unsigned short lds[32768];  // 64KB
  unsigned short* At = lds;
  unsigned short* Bt = lds + 16384;
  const int t = threadIdx.x, l = t & 63, w = t >> 6;
  const int n0 = blockIdx.x * 128, r0 = blockIdx.y * 128;
  const int wr = w >> 1, wc = w & 1;
  // stage A(q rows) and B(kT rows): 2048 16B-chunks each, pre-swizzled source
#pragma unroll
  for (int it = 0; it < 8; it++) {
    const int c = it * 256 + t;
    const int row = c >> 4, ch = c & 15;
    const int chs = ch ^ (row & 7);
    const unsigned short* gA = qb + (size_t)(r0 + row) * 128 + chs * 8;
    const unsigned short* gB = kT + (size_t)(n0 + row) * 128 + chs * 8;
    __builtin_amdgcn_global_load_lds((const __attribute__((address_space(1))) void*)gA,
        (__attribute__((address_space(3))) void*)(At + (size_t)(it * 256 + w * 64) * 8), 16, 0, 0);
    __builtin_amdgcn_global_load_lds((const __attribute__((address_space(1))) void*)gB,
        (__attribute__((address_space(3))) void*)(Bt + (size_t)(it * 256 + w * 64) * 8), 16, 0, 0);
  }
  __syncthreads();
  f32x4 acc[4][4];
#pragma unroll
  for (int i = 0; i < 4; i++)
#pragma unroll
    for (int j = 0; j < 4; j++) acc[i][j] = (f32x4){0.f, 0.f, 0.f, 0.f};
#pragma unroll
  for (int ks = 0; ks < 4; ks++) {
    b16x8 af[4], bf[4];
#pragma unroll
    for (int i = 0; i < 4; i++) {
      const int rl = wr * 64 + i * 16 + (l & 15);
      const int ch = (ks * 4 + (l >> 4)) ^ (rl & 7);
      af[i] = __builtin_bit_cast(b16x8, *(const u16x8*)&At[rl * 128 + ch * 8]);
    }
#pragma unroll
    for (int j = 0; j < 4; j++) {
      const int cl = wc * 64 + j * 16 + (l & 15);
      const int ch = (ks * 4 + (l >> 4)) ^ (cl & 7);
      bf[j] = __builtin_bit_cast(b16x8, *(const u16x8*)&Bt[cl * 128 + ch * 8]);
    }
#pragma unroll
    for (int i = 0; i < 4; i++)
#pragma unroll
      for (int j = 0; j < 4; j++)
        acc[i][j] = __builtin_amdgcn_mfma_f32_16x16x32_bf16(af[i], bf[j], acc[i][j], 0, 0, 0);
  }
  // epilogue: LDS transpose -> coalesced float4 stores
  __syncthreads();
  float* fb = (float*)lds;
  const float rs = 0.08838834764831845f;
#pragma unroll
  for (int i = 0; i < 4; i++)
#pragma unroll
    for (int j = 0; j < 4; j++) {
#pragma unroll
      for (int jj = 0; jj < 4; jj++) {
        const int row = wr * 64 + i * 16 + (l >> 4) * 4 + jj;
        const int col = wc * 64 + j * 16 + (l & 15);
        fb[row * 128 + col] = acc[i][j][jj] * rs;
      }
    }
  __syncthreads();
#pragma unroll
  for (int kk = 0; kk < 16; kk++) {
    const int idx4 = kk * 256 + t;
    const int row = idx4 >> 5, c4 = idx4 & 31;
    *(float4*)(logits + (size_t)(r0 + row) * 8192 + n0 + c4 * 4) = *(const float4*)&fb[row * 128 + c4 * 4];
  }
}

// ---------------- row stats + top-40 (wave-local quarters, then merge) ----------------
__global__ __launch_bounds__(256) void rowstat_topk_kernel(const float* __restrict__ logits,
    float* __restrict__ rowmax, float* __restrict__ rowsum,
    float* __restrict__ topv, int* __restrict__ topi) {
  const int r = blockIdx.x, t = threadIdx.x;
  const int l = t & 63, w = t >> 6;
  const float* row = logits + (size_t)r * 8192;
  float4 v[8];
#pragma unroll
  for (int m = 0; m < 8; m++) v[m] = *(const float4*)(row + w * 2048 + m * 256 + l * 4);

  __shared__ float wvals[4][40];
  __shared__ int   widx[4][40];
  __shared__ float wmax[4], wsum[4];

  // local argmax over this lane's 32 values
  float lv = -3.0e38f; int li = 0;
  unsigned mask = 0u;
#pragma unroll
  for (int m = 0; m < 8; m++) {
    const int gb = w * 2048 + m * 256 + l * 4;
    if (v[m].x > lv) { lv = v[m].x; li = gb; }
    if (v[m].y > lv) { lv = v[m].y; li = gb + 1; }
    if (v[m].z > lv) { lv = v[m].z; li = gb + 2; }
    if (v[m].w > lv) { lv = v[m].w; li = gb + 3; }
  }
  // wave max for global max
  float bm = lv;
#pragma unroll
  for (int off = 32; off; off >>= 1) bm = fmaxf(bm, __shfl_xor(bm, off));
  if (l == 0) wmax[w] = bm;
  __syncthreads();
  const float gmax = fmaxf(fmaxf(wmax[0], wmax[1]), fmaxf(wmax[2], wmax[3]));
  float ls = 0.f;
#pragma unroll
  for (int m = 0; m < 8; m++)
    ls += expf(v[m].x - gmax) + expf(v[m].y - gmax) + expf(v[m].z - gmax) + expf(v[m].w - gmax);
#pragma unroll
  for (int off = 32; off; off >>= 1) ls += __shfl_xor(ls, off);
  if (l == 0) wsum[w] = ls;

  // 40 in-wave argmax iterations for this quarter
  for (int it = 0; it < 40; ++it) {
    float cv = lv; int ci = li;
#pragma unroll
    for (int off = 32; off; off >>= 1) {
      const float ov = __shfl_xor(cv, off);
      const int oi = __shfl_xor(ci, off);
      if (ov > cv || (ov == cv && oi < ci)) { cv = ov; ci = oi; }
    }
    if (l == 0) { wvals[w][it] = cv; widx[w][it] = ci; }
    if (((ci >> 2) & 63) == l) {
      const int m = (ci & 2047) >> 8, e = ci & 3;
      mask |= 1u << (m * 4 + e);
      lv = -3.0e38f; li = 0;
#pragma unroll
      for (int mm = 0; mm < 8; mm++) {
        const int gb = w * 2048 + mm * 256 + l * 4;
        if (!(mask & (1u << (mm * 4 + 0))) && v[mm].x > lv) { lv = v[mm].x; li = gb; }
        if (!(mask & (1u << (mm * 4 + 1))) && v[mm].y > lv) { lv = v[mm].y; li = gb + 1; }
        if (!(mask & (1u << (mm * 4 + 2))) && v[mm].z > lv) { lv = v[mm].z; li = gb + 2; }
        if (!(mask & (1u << (mm * 4 + 3))) && v[mm].w > lv) { lv = v[mm].w; li = gb + 3; }
      }
    }
  }
  __syncthreads();
  const float gsum = wsum[0] + wsum[1] + wsum[2] + wsum[3];
  if (t == 0) { rowmax[r] = gmax; rowsum[r] = gsum; }

  // merge 160 candidates on wave 0
  if (w == 0) {
    float c0 = wvals[l >> 5 ? 1 : 0][0]; // placeholder init, overwritten below
    int i0n;
    // lane slots: l, l+64, l+128(if l<32)
    c0 = ((const float*)wvals)[l];          i0n = ((const int*)widx)[l];
    float c1 = ((const float*)wvals)[l + 64];  int i1n = ((const int*)widx)[l + 64];
    float c2 = (l < 32) ? ((const float*)wvals)[l + 128] : -3.0e38f;
    int   i2n = (l < 32) ? ((const int*)widx)[l + 128] : 0x7fffffff;
    const float rgs = 1.0f / gsum;
    for (int it = 0; it < 40; ++it) {
      float bv2 = c0; int bi2 = i0n;
      if (c1 > bv2 || (c1 == bv2 && i1n < bi2)) { bv2 = c1; bi2 = i1n; }
      if (c2 > bv2 || (c2 == bv2 && i2n < bi2)) { bv2 = c2; bi2 = i2n; }
      float cv = bv2; int ci = bi2;
#pragma unroll
      for (int off = 32; off; off >>= 1) {
        const float ov = __shfl_xor(cv, off);
        const int oi = __shfl_xor(ci, off);
        if (ov > cv || (ov == cv && oi < ci)) { cv = ov; ci = oi; }
      }
      if (l == 0) {
        topi[r * 40 + it] = ci;
        topv[r * 40 + it] = expf(cv - gmax) * rgs;
      }
      if (ci == i0n && cv == c0) { c0 = -3.0e38f; i0n = 0x7fffffff; }
      else if (ci == i1n && cv == c1) { c1 = -3.0e38f; i1n = 0x7fffffff; }
      else if (ci == i2n && cv == c2) { c2 = -3.0e38f; i2n = 0x7fffffff; }
    }
  }
}

// ---------------- GEMM2 (MFMA): pvpart[chunk][4096][128] = softmax(logits) @ V ----------------
__global__ __launch_bounds__(256) void gemm2_mfma(const float* __restrict__ logits,
    const unsigned short* __restrict__ vT, const float* __restrict__ rowmax,
    const float* __restrict__ rowsum, float* __restrict__ pvpart) {
  __shared__ __attribute__((aligned(16))) unsigned short lds[32768];  // 64KB
  unsigned short* At = lds;           // P tile [128][64] bf16 (swizzled)
  unsigned short* Bt = lds + 8192;    // vT tile [128 c][64 k] bf16 (swizzled)
  const int t = threadIdx.x, l = t & 63, w = t >> 6;
  const int bx = blockIdx.x;          // k-chunk (0..7), 1024 wide
  const int by = blockIdx.y;          // row block (0..31)
  const int r0 = by * 128;
  const int kb0 = bx * 1024;
  const int wr = w >> 1, wc = w & 1;
  const int prow = t >> 1, pk = (t & 1) * 32;
  const float rm = rowmax[r0 + prow];
  const float ri = 1.0f / rowsum[r0 + prow];

  f32x4 acc[4][4];
#pragma unroll
  for (int i = 0; i < 4; i++)
#pragma unroll
    for (int j = 0; j < 4; j++) acc[i][j] = (f32x4){0.f, 0.f, 0.f, 0.f};

  for (int ks = 0; ks < 16; ks++) {
    const int k0 = kb0 + ks * 64;
    __syncthreads();
    // stage B: 1024 chunks of 16B from vT rows (pre-swizzled source)
#pragma unroll
    for (int it = 0; it < 4; it++) {
      const int c = it * 256 + t;
      const int rowc = c >> 3, ch = c & 7;
      const int chs = ch ^ (rowc & 7);
      const unsigned short* gB = vT + (size_t)rowc * 8192 + k0 + chs * 8;
      __builtin_amdgcn_global_load_lds((const __attribute__((address_space(1))) void*)gB,
          (__attribute__((address_space(3))) void*)(Bt + (size_t)(it * 256 + w * 64) * 8), 16, 0, 0);
    }
    // stage A: read logits [128][64] fp32, softmax, bf16, swizzled ds_write
    const float* lsrc = logits + (size_t)(r0 + prow) * 8192 + k0 + pk;
#pragma unroll
    for (int c8 = 0; c8 < 4; c8++) {
      float4 v0 = *(const float4*)(lsrc + c8 * 8);
      float4 v1 = *(const float4*)(lsrc + c8 * 8 + 4);
      u16x8 pkd;
      pkd[0] = f2bf(expf(v0.x - rm) * ri); pkd[1] = f2bf(expf(v0.y - rm) * ri);
      pkd[2] = f2bf(expf(v0.z - rm) * ri); pkd[3] = f2bf(expf(v0.w - rm) * ri);
      pkd[4] = f2bf(expf(v1.x - rm) * ri); pkd[5] = f2bf(expf(v1.y - rm) * ri);
      pkd[6] = f2bf(expf(v1.z - rm) * ri); pkd[7] = f2bf(expf(v1.w - rm) * ri);
      const int chunkidx = (t & 1) * 4 + c8;
      const int phys = chunkidx ^ (prow & 7);
      *(u16x8*)&At[prow * 64 + phys * 8] = pkd;
    }
    __syncthreads();
#pragma unroll
    for (int s = 0; s < 2; s++) {
      b16x8 af[4], bf[4];
#pragma unroll
      for (int i = 0; i < 4; i++) {
        const int rl = wr * 64 + i * 16 + (l & 15);
        const int ch = (s * 4 + (l >> 4)) ^ (rl & 7);
        af[i] = __builtin_bit_cast(b16x8, *(const u16x8*)&At[rl * 64 + ch * 8]);
      }
#pragma unroll
      for (int j = 0; j < 4; j++) {
        const int cl = wc * 64 + j * 16 + (l & 15);
        const int ch = (s * 4 + (l >> 4)) ^ (cl & 7);
        bf[j] = __builtin_bit_cast(b16x8, *(const u16x8*)&Bt[cl * 64 + ch * 8]);
      }
#pragma unroll
      for (int i = 0; i < 4; i++)
#pragma unroll
        for (int j = 0; j < 4; j++)
          acc[i][j] = __builtin_amdgcn_mfma_f32_16x16x32_bf16(af[i], bf[j], acc[i][j], 0, 0, 0);
    }
  }
  // epilogue
  __syncthreads();
  float* fb = (float*)lds;
#pragma unroll
  for (int i = 0; i < 4; i++)
#pragma unroll
    for (int j = 0; j < 4; j++)
#pragma unroll
      for (int jj = 0; jj < 4; jj++) {
        const int row = wr * 64 + i * 16 + (l >> 4) * 4 + jj;
        const int col = wc * 64 + j * 16 + (l & 15);
        fb[row * 128 + col] = acc[i][j][jj];
      }
  __syncthreads();
#pragma unroll
  for (int kk = 0; kk < 16; kk++) {
    const int idx4 = kk * 256 + t;
    const int row = idx4 >> 5, c4 = idx4 & 31;
    *(float4*)(pvpart + ((size_t)bx * 4096 + r0 + row) * 128 + c4 * 4) = *(const float4*)&fb[row * 128 + c4 * 4];
  }
}

__global__ __launch_bounds__(256) void pvred_kernel(const float* __restrict__ pvpart,
    float* __restrict__ o2, float* __restrict__ o3) {
  const int idx4 = blockIdx.x * 256 + threadIdx.x;
  float4 s; s.x = s.y = s.z = s.w = 0.f;
#pragma unroll
  for (int ch = 0; ch < 8; ch++) {
    float4 p = *(const float4*)(pvpart + (size_t)ch * 524288 + (size_t)idx4 * 4);
    s.x += p.x; s.y += p.y; s.z += p.z; s.w += p.w;
  }
  *(float4*)(o2 + (size_t)idx4 * 4) = s;
  *(float4*)(o3 + (size_t)idx4 * 4) = s;
}

__global__ __launch_bounds__(256) void seedscatter_kernel(const int* __restrict__ topi,
    const float* __restrict__ topv, const int* __restrict__ invperm,
    float* __restrict__ out0) {
  const int b = blockIdx.x, t = threadIdx.x;
  int s = 0;
  for (int e = t; e < 640; e += 256) s += topi[b * 640 + e];
#pragma unroll
  for (int off = 32; off; off >>= 1) s += __shfl_xor(s, off);
  __shared__ int sred[4];
  if ((t & 63) == 0) sred[t >> 6] = s;
  __syncthreads();
  const int total = sred[0] + sred[1] + sred[2] + sred[3];
  const float avg = (float)total / 640.0f;
  const int sd = ((int)floorf(avg / 2048.0f)) & 3;
  const int* ip = invperm + sd * 8192;
  for (int e = t; e < 640; e += 256) {
    const int q = e / 40;
    const int i = topi[b * 640 + e];
    const float val = topv[b * 640 + e];
    out0[((size_t)(b * 16 + q)) * 8192 + ip[i]] = val;
  }
}

extern "C" void kernel_launch(void* const* d_in, const int* in_sizes, int n_in,
                              void* d_out, int out_size, void* d_ws, size_t ws_size,
                              hipStream_t stream) {
  const float* x   = (const float*)d_in[0];
  const float* emb = (const float*)d_in[1];
  const float* Wq  = (const float*)d_in[2];
  const float* bq  = (const float*)d_in[3];
  const float* Wv  = (const float*)d_in[4];
  const float* bv  = (const float*)d_in[5];
  const float* bng = (const float*)d_in[6];
  const float* bnb = (const float*)d_in[7];
  const float* lng = (const float*)d_in[8];
  const float* lnb = (const float*)d_in[9];

  float* out0  = (float*)d_out;          // attn_w_flat (also logits scratch)
  float* outq  = out0 + 33554432;        // q
  float* outap = outq + 524288;          // applied
  float* outaf = outap + 524288;         // applied_flat

  float* wsf    = (float*)d_ws;
  float* kbuf   = wsf;                     // 1048576
  float* vbuf   = kbuf + 1048576;          // 1048576
  float* qraw   = vbuf + 1048576;          // 524288
  float* bnpart = qraw + 524288;           // 8192
  float* bnstat = bnpart + 8192;           // 256
  float* rowmax = bnstat + 256;            // 4096
  float* rowsum = rowmax + 4096;           // 4096
  float* pvpart = rowsum + 4096;           // 8*524288 = 4194304
  float* topv   = pvpart + 4194304;        // 163840
  int*   topi    = (int*)(topv + 163840);  // 163840
  int*   invperm = topi + 163840;          // 32768
  unsigned short* qb = (unsigned short*)(invperm + 32768);  // 524288 ushort
  unsigned short* kT = qb + 524288;                         // 1048576 ushort
  unsigned short* vT = kT + 1048576;                        // 1048576 ushort

  perm_kernel<<<4, 1024, 65536, stream>>>(invperm);
  qraw_kernel<<<dim3(64, 4), 256, 0, stream>>>(x, Wq, bq, qraw);
  bnpart_kernel<<<32, 256, 0, stream>>>(qraw, bnpart);
  bnfin_kernel<<<1, 128, 0, stream>>>(bnpart, bng, bnb, bnstat);
  qnorm_kernel<<<512, 256, 0, stream>>>(qraw, bnstat, outq, qb);
  lnv_kernel<<<512, 256, 0, stream>>>(emb, Wv, bv, lng, lnb, kbuf, vbuf);
  ktrans_kernel<<<128, 256, 0, stream>>>(kbuf, kT);
  vtrans_kernel<<<128, 256, 0, stream>>>(vbuf, vT);
  gemm1_mfma<<<dim3(64, 32), 256, 0, stream>>>(qb, kT, out0);
  rowstat_topk_kernel<<<4096, 256, 0, stream>>>(out0, rowmax, rowsum, topv, topi);
  gemm2_mfma<<<dim3(8, 32), 256, 0, stream>>>(out0, vT, rowmax, rowsum, pvpart);
  pvred_kernel<<<512, 256, 0, stream>>>(pvpart, outap, outaf);
  hipMemsetAsync(d_out, 0, (size_t)33554432 * 4, stream);
  seedscatter_kernel<<<256, 256, 0, stream>>>(topi, topv, invperm, out0);
}

// Round 3
// 588.864 us; speedup vs baseline: 1.5382x; 1.3827x over previous
//
#include <hip/hip_runtime.h>
#include <hip/hip_bf16.h>
#include <stdint.h>

// N=8192, C1=512, C2=128, M=4, B=256, TOPK=40, R=B*M*M=4096
#define EPSF 1e-5f

typedef __bf16 b16x8 __attribute__((ext_vector_type(8)));
typedef float f32x4 __attribute__((ext_vector_type(4)));
typedef unsigned short u16x8 __attribute__((ext_vector_type(8)));

static __device__ __forceinline__ unsigned short f2bf(float f) {
  __hip_bfloat16 h = __float2bfloat16(f);
  return __builtin_bit_cast(unsigned short, h);
}

// ---------------- RNG (JAX threefry, partitionable) ----------------
#define RNG_BITS_SECOND 1

__device__ __forceinline__ void threefry2x32(uint32_t k0, uint32_t k1,
                                             uint32_t c0, uint32_t c1,
                                             uint32_t& o0, uint32_t& o1) {
  const uint32_t ks2 = k0 ^ k1 ^ 0x1BD11BDAu;
  uint32_t x0 = c0 + k0, x1 = c1 + k1;
#define TFR(r) { x0 += x1; x1 = (x1 << (r)) | (x1 >> (32 - (r))); x1 ^= x0; }
  TFR(13) TFR(15) TFR(26) TFR(6)
  x0 += k1;  x1 += ks2 + 1u;
  TFR(17) TFR(29) TFR(16) TFR(24)
  x0 += ks2; x1 += k0 + 2u;
  TFR(13) TFR(15) TFR(26) TFR(6)
  x0 += k0;  x1 += k1 + 3u;
  TFR(17) TFR(29) TFR(16) TFR(24)
  x0 += k1;  x1 += ks2 + 4u;
  TFR(13) TFR(15) TFR(26) TFR(6)
  x0 += ks2; x1 += k0 + 5u;
#undef TFR
  o0 = x0; o1 = x1;
}

__device__ __forceinline__ void bitonic_sort8192(unsigned long long* lds, int t, int NT) {
  for (unsigned k = 2; k <= 8192u; k <<= 1) {
    for (unsigned j = k >> 1; j > 0; j >>= 1) {
      for (unsigned i = (unsigned)t; i < 8192u; i += (unsigned)NT) {
        unsigned l = i ^ j;
        if (l > i) {
          unsigned long long a = lds[i], b = lds[l];
          const bool up = ((i & k) == 0u);
          if ((a > b) == up) { lds[i] = b; lds[l] = a; }
        }
      }
      __syncthreads();
    }
  }
}

__global__ void perm_kernel(int* __restrict__ invperm) {
  extern __shared__ unsigned long long lds[];
  const int s = blockIdx.x, t = threadIdx.x, NT = blockDim.x;
  const uint32_t K0 = 0u, K1 = (uint32_t)s;
  uint32_t k1a, k1b, s1a, s1b, s2a, s2b, t0, t1;
  threefry2x32(K0, K1, 0u, 0u, k1a, k1b);
  threefry2x32(K0, K1, 0u, 1u, s1a, s1b);
  threefry2x32(k1a, k1b, 0u, 1u, s2a, s2b);
  for (int i = t; i < 8192; i += NT) {
    uint32_t bits;
    threefry2x32(s1a, s1b, 0u, (uint32_t)i, t0, t1);
    bits = RNG_BITS_SECOND ? t1 : t0;
    lds[i] = ((unsigned long long)bits << 13) | (unsigned long long)i;
  }
  __syncthreads();
  bitonic_sort8192(lds, t, NT);
  for (int i = t; i < 8192; i += NT) {
    unsigned long long val = lds[i] & 8191ull;
    uint32_t bits;
    threefry2x32(s2a, s2b, 0u, (uint32_t)i, t0, t1);
    bits = RNG_BITS_SECOND ? t1 : t0;
    lds[i] = ((unsigned long long)bits << 26) |
             ((unsigned long long)(unsigned)i << 13) | val;
  }
  __syncthreads();
  bitonic_sort8192(lds, t, NT);
  for (int i = t; i < 8192; i += NT) {
    int val = (int)(lds[i] & 8191ull);
    invperm[s * 8192 + val] = i;
  }
}

// ---------------- q path ----------------
__global__ __launch_bounds__(256) void qraw_kernel(const float* __restrict__ x,
    const float* __restrict__ Wq, const float* __restrict__ bq,
    float* __restrict__ qraw) {
  __shared__ float ea[16][128];
  __shared__ float wq[128][132];
  const int t = threadIdx.x;
  const int g = blockIdx.x;
  const int m2 = blockIdx.y;
  for (int i = t; i < 512; i += 256) {
    float4 xx = *(const float4*)(x + (size_t)g * 2048 + i * 4);
    *(float4*)&ea[i >> 5][(i & 31) * 4] = xx;
  }
  for (int i = t; i < 4096; i += 256) {
    float4 ww = *(const float4*)(Wq + (size_t)m2 * 16384 + i * 4);
    *(float4*)&wq[i >> 5][(i & 31) * 4] = ww;
  }
  __syncthreads();
  const int row = t >> 4, j = t & 15;
  float acc[8] = {0.f,0.f,0.f,0.f,0.f,0.f,0.f,0.f};
  for (int d = 0; d < 128; d++) {
    const float xv = ea[row][d];
#pragma unroll
    for (int cc = 0; cc < 8; cc++) acc[cc] += xv * wq[j + cc * 16][d];
  }
  const int r = (g * 16 + row) * 4 + m2;
#pragma unroll
  for (int cc = 0; cc < 8; cc++) {
    const int c = j + cc * 16;
    qraw[(size_t)r * 128 + c] = acc[cc] + bq[m2 * 128 + c];
  }
}

__global__ __launch_bounds__(256) void bnpart_kernel(const float* __restrict__ qraw,
                                                     float* __restrict__ bnpart) {
  __shared__ float a1[256], a2[256];
  const int t = threadIdx.x, c = t & 127, h = t >> 7;
  float s1 = 0.f, s2 = 0.f;
  for (int i = 0; i < 64; i++) {
    float xv = qraw[(size_t)(blockIdx.x * 128 + h + 2 * i) * 128 + c];
    s1 += xv; s2 += xv * xv;
  }
  a1[t] = s1; a2[t] = s2;
  __syncthreads();
  if (t < 128) {
    bnpart[blockIdx.x * 256 + t]       = a1[t] + a1[t + 128];
    bnpart[blockIdx.x * 256 + 128 + t] = a2[t] + a2[t + 128];
  }
}

__global__ void bnfin_kernel(const float* __restrict__ bnpart,
                             const float* __restrict__ gamma,
                             const float* __restrict__ beta,
                             float* __restrict__ bnstat) {
  const int c = threadIdx.x;
  float s1 = 0.f, s2 = 0.f;
  for (int i = 0; i < 32; i++) { s1 += bnpart[i * 256 + c]; s2 += bnpart[i * 256 + 128 + c]; }
  const float mu  = s1 * (1.0f / 4096.0f);
  const float var = s2 * (1.0f / 4096.0f) - mu * mu;
  const float sc  = rsqrtf(var + EPSF) * gamma[c];
  bnstat[c]       = sc;
  bnstat[128 + c] = beta[c] - mu * sc;
}

__global__ __launch_bounds__(256) void qnorm_kernel(const float* __restrict__ qraw,
    const float* __restrict__ bnstat, float* __restrict__ outq,
    unsigned short* __restrict__ qb) {
  const int idx4 = blockIdx.x * 256 + threadIdx.x;
  float4 xv = *(const float4*)(qraw + (size_t)idx4 * 4);
  const int c0 = (idx4 * 4) & 127;
  float4 sc = *(const float4*)(bnstat + c0);
  float4 sh = *(const float4*)(bnstat + 128 + c0);
  float4 o;
  o.x = xv.x * sc.x + sh.x; o.y = xv.y * sc.y + sh.y;
  o.z = xv.z * sc.z + sh.z; o.w = xv.w * sc.w + sh.w;
  *(float4*)(outq + (size_t)idx4 * 4) = o;
  ushort4 ob;
  ob.x = f2bf(o.x); ob.y = f2bf(o.y); ob.z = f2bf(o.z); ob.w = f2bf(o.w);
  *(ushort4*)(qb + (size_t)idx4 * 4) = ob;
}

// ---------------- LN(emb) -> kbuf, emb@Wv^T+bv -> vbuf ----------------
__global__ __launch_bounds__(256) void lnv_kernel(const float* __restrict__ emb,
    const float* __restrict__ Wv, const float* __restrict__ bv,
    const float* __restrict__ lng, const float* __restrict__ lnb,
    float* __restrict__ kbuf, float* __restrict__ vbuf) {
  __shared__ float ea[16][128];
  __shared__ float wv[128][132];
  const int t = threadIdx.x;
  const int r0 = blockIdx.x * 16;
  for (int i = t; i < 512; i += 256) {
    float4 xx = *(const float4*)(emb + (size_t)r0 * 128 + i * 4);
    *(float4*)&ea[i >> 5][(i & 31) * 4] = xx;
  }
  for (int i = t; i < 4096; i += 256) {
    float4 ww = *(const float4*)(Wv + (size_t)i * 4);
    *(float4*)&wv[i >> 5][(i & 31) * 4] = ww;
  }
  __syncthreads();
  const int row = t >> 4, j = t & 15;
  float s1 = 0.f, s2 = 0.f;
#pragma unroll
  for (int m = 0; m < 8; m++) { float xv = ea[row][j + m * 16]; s1 += xv; s2 += xv * xv; }
#pragma unroll
  for (int off = 8; off; off >>= 1) {
    s1 += __shfl_xor(s1, off, 16);
    s2 += __shfl_xor(s2, off, 16);
  }
  const float mu   = s1 * 0.0078125f;
  const float var  = s2 * 0.0078125f - mu * mu;
  const float rstd = rsqrtf(var + EPSF);
#pragma unroll
  for (int m = 0; m < 8; m++) {
    const int d = j + m * 16;
    kbuf[(size_t)(r0 + row) * 128 + d] = (ea[row][d] - mu) * rstd * lng[d] + lnb[d];
  }
  float acc[8] = {0.f,0.f,0.f,0.f,0.f,0.f,0.f,0.f};
  for (int d = 0; d < 128; d++) {
    const float xv = ea[row][d];
#pragma unroll
    for (int cc = 0; cc < 8; cc++) acc[cc] += xv * wv[j + cc * 16][d];
  }
#pragma unroll
  for (int cc = 0; cc < 8; cc++) {
    const int c = j + cc * 16;
    vbuf[(size_t)(r0 + row) * 128 + c] = acc[cc] + bv[c];
  }
}

// ---------------- bf16 transposes for MFMA B-operands ----------------
__global__ __launch_bounds__(256) void ktrans_kernel(const float* __restrict__ kbuf,
                                                     unsigned short* __restrict__ kT) {
  __shared__ unsigned short s[64][136];
  const int b = blockIdx.x, t = threadIdx.x;
  const int k = t >> 1, half = t & 1;
  const float* src = kbuf + (size_t)(k * 64 + (b >> 1)) * 128 + (b & 1) * 64 + half * 32;
#pragma unroll
  for (int i = 0; i < 8; i++) {
    float4 v = *(const float4*)(src + i * 4);
    const int dn = half * 32 + i * 4;
    s[dn + 0][k] = f2bf(v.x); s[dn + 1][k] = f2bf(v.y);
    s[dn + 2][k] = f2bf(v.z); s[dn + 3][k] = f2bf(v.w);
  }
  __syncthreads();
  const int dn = t >> 2, q = t & 3;
  unsigned short* dst = kT + (size_t)(b * 64 + dn) * 128 + q * 32;
#pragma unroll
  for (int j = 0; j < 4; j++)
    *(int4*)(dst + j * 8) = *(const int4*)&s[dn][q * 32 + j * 8];
}

__global__ __launch_bounds__(256) void vtrans_kernel(const float* __restrict__ vbuf,
                                                     unsigned short* __restrict__ vT) {
  __shared__ unsigned short s[128][72];
  const int b = blockIdx.x, t = threadIdx.x;
  const int i0 = b * 64;
  const int di = t >> 2, q = t & 3;
  const float* src = vbuf + (size_t)(i0 + di) * 128 + q * 32;
#pragma unroll
  for (int i = 0; i < 8; i++) {
    float4 v = *(const float4*)(src + i * 4);
    const int c = q * 32 + i * 4;
    s[c + 0][di] = f2bf(v.x); s[c + 1][di] = f2bf(v.y);
    s[c + 2][di] = f2bf(v.z); s[c + 3][di] = f2bf(v.w);
  }
  __syncthreads();
  const int c = t >> 1, half = t & 1;
  unsigned short* dst = vT + (size_t)c * 8192 + i0 + half * 32;
#pragma unroll
  for (int j = 0; j < 4; j++)
    *(int4*)(dst + j * 8) = *(const int4*)&s[c][half * 32 + j * 8];
}

// ---------------- GEMM1 (MFMA): logits[4096][8192] = qb @ kT^T / sqrt(128) ----------------
__global__ __launch_bounds__(256) void gemm1_mfma(const unsigned short* __restrict__ qb,
    const unsigned short* __restrict__ kT, float* __restrict__ logits) {
  __shared__ __attribute__((aligned(16))) unsigned short lds[32768];  // 64KB
  unsigned short* At = lds;
  unsigned short* Bt = lds + 16384;
  const int t = threadIdx.x, l = t & 63, w = t >> 6;
  const int n0 = blockIdx.x * 128, r0 = blockIdx.y * 128;
  const int wr = w >> 1, wc = w & 1;
#pragma unroll
  for (int it = 0; it < 8; it++) {
    const int c = it * 256 + t;
    const int row = c >> 4, ch = c & 15;
    const int chs = ch ^ (row & 7);
    const unsigned short* gA = qb + (size_t)(r0 + row) * 128 + chs * 8;
    const unsigned short* gB = kT + (size_t)(n0 + row) * 128 + chs * 8;
    __builtin_amdgcn_global_load_lds((const __attribute__((address_space(1))) void*)gA,
        (__attribute__((address_space(3))) void*)(At + (size_t)(it * 256 + w * 64) * 8), 16, 0, 0);
    __builtin_amdgcn_global_load_lds((const __attribute__((address_space(1))) void*)gB,
        (__attribute__((address_space(3))) void*)(Bt + (size_t)(it * 256 + w * 64) * 8), 16, 0, 0);
  }
  __syncthreads();
  f32x4 acc[4][4];
#pragma unroll
  for (int i = 0; i < 4; i++)
#pragma unroll
    for (int j = 0; j < 4; j++) acc[i][j] = (f32x4){0.f, 0.f, 0.f, 0.f};
#pragma unroll
  for (int ks = 0; ks < 4; ks++) {
    b16x8 af[4], bf[4];
#pragma unroll
    for (int i = 0; i < 4; i++) {
      const int rl = wr * 64 + i * 16 + (l & 15);
      const int ch = (ks * 4 + (l >> 4)) ^ (rl & 7);
      af[i] = __builtin_bit_cast(b16x8, *(const u16x8*)&At[rl * 128 + ch * 8]);
    }
#pragma unroll
    for (int j = 0; j < 4; j++) {
      const int cl = wc * 64 + j * 16 + (l & 15);
      const int ch = (ks * 4 + (l >> 4)) ^ (cl & 7);
      bf[j] = __builtin_bit_cast(b16x8, *(const u16x8*)&Bt[cl * 128 + ch * 8]);
    }
#pragma unroll
    for (int i = 0; i < 4; i++)
#pragma unroll
      for (int j = 0; j < 4; j++)
        acc[i][j] = __builtin_amdgcn_mfma_f32_16x16x32_bf16(af[i], bf[j], acc[i][j], 0, 0, 0);
  }
  __syncthreads();
  float* fb = (float*)lds;
  const float rs = 0.08838834764831845f;
#pragma unroll
  for (int i = 0; i < 4; i++)
#pragma unroll
    for (int j = 0; j < 4; j++) {
#pragma unroll
      for (int jj = 0; jj < 4; jj++) {
        const int row = wr * 64 + i * 16 + (l >> 4) * 4 + jj;
        const int col = wc * 64 + j * 16 + (l & 15);
        fb[row * 128 + col] = acc[i][j][jj] * rs;
      }
    }
  __syncthreads();
#pragma unroll
  for (int kk = 0; kk < 16; kk++) {
    const int idx4 = kk * 256 + t;
    const int row = idx4 >> 5, c4 = idx4 & 31;
    *(float4*)(logits + (size_t)(r0 + row) * 8192 + n0 + c4 * 4) = *(const float4*)&fb[row * 128 + c4 * 4];
  }
}

// ---------------- row stats + top-40 via threshold-select + rank ----------------
__global__ __launch_bounds__(256) void rowstat_topk_kernel(const float* __restrict__ logits,
    float* __restrict__ rowmax, float* __restrict__ rowsum,
    float* __restrict__ topv, int* __restrict__ topi) {
  const int r = blockIdx.x, t = threadIdx.x;
  const int l = t & 63, w = t >> 6;
  const float* row = logits + (size_t)r * 8192;
  float4 v[8];
#pragma unroll
  for (int m = 0; m < 8; m++) v[m] = *(const float4*)(row + m * 1024 + t * 4);

  __shared__ float sredf[4];
  __shared__ int scnt[16];
  __shared__ unsigned long long keys[1024];
  __shared__ int lcnt;

  // block max
  float bm = -3.0e38f;
#pragma unroll
  for (int m = 0; m < 8; m++)
    bm = fmaxf(bm, fmaxf(fmaxf(v[m].x, v[m].y), fmaxf(v[m].z, v[m].w)));
#pragma unroll
  for (int off = 32; off; off >>= 1) bm = fmaxf(bm, __shfl_xor(bm, off));
  if (l == 0) sredf[w] = bm;
  __syncthreads();
  const float gmax = fmaxf(fmaxf(sredf[0], sredf[1]), fmaxf(sredf[2], sredf[3]));

  // block sum of exp
  float ls = 0.f;
#pragma unroll
  for (int m = 0; m < 8; m++)
    ls += expf(v[m].x - gmax) + expf(v[m].y - gmax) + expf(v[m].z - gmax) + expf(v[m].w - gmax);
#pragma unroll
  for (int off = 32; off; off >>= 1) ls += __shfl_xor(ls, off);
  __syncthreads();
  if (l == 0) sredf[w] = ls;
  __syncthreads();
  const float gsum = sredf[0] + sredf[1] + sredf[2] + sredf[3];
  if (t == 0) { rowmax[r] = gmax; rowsum[r] = gsum; }

  // threshold search: first theta (on a widening grid) with count >= 40
  float theta = -3.0e38f;
  bool found = false;
  for (int trial = 0; trial < 8 && !found; trial++) {
    const float base = gmax - 8.0f * (float)trial;
    int c[16];
#pragma unroll
    for (int j = 0; j < 16; j++) c[j] = 0;
#pragma unroll
    for (int m = 0; m < 8; m++) {
#pragma unroll
      for (int j = 0; j < 16; j++) {
        const float th = base - 0.5f * (float)(j + 1);
        c[j] += (v[m].x >= th) + (v[m].y >= th) + (v[m].z >= th) + (v[m].w >= th);
      }
    }
#pragma unroll
    for (int j = 0; j < 16; j++) {
#pragma unroll
      for (int off = 32; off; off >>= 1) c[j] += __shfl_xor(c[j], off);
    }
    if (t < 16) scnt[t] = 0;
    __syncthreads();
    if (l == 0) {
#pragma unroll
      for (int j = 0; j < 16; j++) atomicAdd(&scnt[j], c[j]);
    }
    __syncthreads();
    for (int j = 0; j < 16; j++) {
      if (scnt[j] >= 40) { theta = base - 0.5f * (float)(j + 1); found = true; break; }
    }
    __syncthreads();
  }

  // compact candidates >= theta into LDS as composite keys
  if (t == 0) lcnt = 0;
  __syncthreads();
#pragma unroll
  for (int m = 0; m < 8; m++) {
    const int gb = m * 1024 + t * 4;
    const float vals[4] = {v[m].x, v[m].y, v[m].z, v[m].w};
#pragma unroll
    for (int e = 0; e < 4; e++) {
      if (vals[e] >= theta) {
        const int pos = atomicAdd(&lcnt, 1);
        if (pos < 1024) {
          const uint32_t s = __float_as_uint(vals[e]);
          const uint32_t mkey = (s & 0x80000000u) ? ~s : (s | 0x80000000u);
          keys[pos] = ((unsigned long long)(~mkey) << 32) | (unsigned)(gb + e);
        }
      }
    }
  }
  __syncthreads();
  const int cnt = min(lcnt, 1024);
  const float rgs = 1.0f / gsum;
  for (int i = t; i < cnt; i += 256) {
    const unsigned long long K = keys[i];
    int rank = 0;
#pragma unroll 4
    for (int p = 0; p < cnt; p++) rank += (keys[p] < K) ? 1 : 0;
    if (rank < 40) {
      const uint32_t desc = (uint32_t)(K >> 32);
      const uint32_t mkey = ~desc;
      const uint32_t sb = (mkey & 0x80000000u) ? (mkey & 0x7FFFFFFFu) : ~mkey;
      const float val = __uint_as_float(sb);
      topi[r * 40 + rank] = (int)(K & 0xFFFFFFFFu);
      topv[r * 40 + rank] = expf(val - gmax) * rgs;
    }
  }
}

// ---------------- GEMM2 (MFMA): pvpart[chunk][4096][128] = softmax(logits) @ V ----------------
__global__ __launch_bounds__(256) void gemm2_mfma(const float* __restrict__ logits,
    const unsigned short* __restrict__ vT, const float* __restrict__ rowmax,
    const float* __restrict__ rowsum, float* __restrict__ pvpart) {
  __shared__ __attribute__((aligned(16))) unsigned short lds[32768];  // 64KB
  unsigned short* At = lds;           // P tile [128][64] bf16 (swizzled)
  unsigned short* Bt = lds + 8192;    // vT tile [128 c][64 k] bf16 (swizzled)
  const int t = threadIdx.x, l = t & 63, w = t >> 6;
  const int bx = blockIdx.x;
  const int by = blockIdx.y;
  const int r0 = by * 128;
  const int kb0 = bx * 1024;
  const int wr = w >> 1, wc = w & 1;
  const int prow = t >> 1, pk = (t & 1) * 32;
  const float rm = rowmax[r0 + prow];
  const float ri = 1.0f / rowsum[r0 + prow];

  f32x4 acc[4][4];
#pragma unroll
  for (int i = 0; i < 4; i++)
#pragma unroll
    for (int j = 0; j < 4; j++) acc[i][j] = (f32x4){0.f, 0.f, 0.f, 0.f};

  for (int ks = 0; ks < 16; ks++) {
    const int k0 = kb0 + ks * 64;
    __syncthreads();
#pragma unroll
    for (int it = 0; it < 4; it++) {
      const int c = it * 256 + t;
      const int rowc = c >> 3, ch = c & 7;
      const int chs = ch ^ (rowc & 7);
      const unsigned short* gB = vT + (size_t)rowc * 8192 + k0 + chs * 8;
      __builtin_amdgcn_global_load_lds((const __attribute__((address_space(1))) void*)gB,
          (__attribute__((address_space(3))) void*)(Bt + (size_t)(it * 256 + w * 64) * 8), 16, 0, 0);
    }
    const float* lsrc = logits + (size_t)(r0 + prow) * 8192 + k0 + pk;
#pragma unroll
    for (int c8 = 0; c8 < 4; c8++) {
      float4 v0 = *(const float4*)(lsrc + c8 * 8);
      float4 v1 = *(const float4*)(lsrc + c8 * 8 + 4);
      u16x8 pkd;
      pkd[0] = f2bf(expf(v0.x - rm) * ri); pkd[1] = f2bf(expf(v0.y - rm) * ri);
      pkd[2] = f2bf(expf(v0.z - rm) * ri); pkd[3] = f2bf(expf(v0.w - rm) * ri);
      pkd[4] = f2bf(expf(v1.x - rm) * ri); pkd[5] = f2bf(expf(v1.y - rm) * ri);
      pkd[6] = f2bf(expf(v1.z - rm) * ri); pkd[7] = f2bf(expf(v1.w - rm) * ri);
      const int chunkidx = (t & 1) * 4 + c8;
      const int phys = chunkidx ^ (prow & 7);
      *(u16x8*)&At[prow * 64 + phys * 8] = pkd;
    }
    __syncthreads();
#pragma unroll
    for (int s = 0; s < 2; s++) {
      b16x8 af[4], bf[4];
#pragma unroll
      for (int i = 0; i < 4; i++) {
        const int rl = wr * 64 + i * 16 + (l & 15);
        const int ch = (s * 4 + (l >> 4)) ^ (rl & 7);
        af[i] = __builtin_bit_cast(b16x8, *(const u16x8*)&At[rl * 64 + ch * 8]);
      }
#pragma unroll
      for (int j = 0; j < 4; j++) {
        const int cl = wc * 64 + j * 16 + (l & 15);
        const int ch = (s * 4 + (l >> 4)) ^ (cl & 7);
        bf[j] = __builtin_bit_cast(b16x8, *(const u16x8*)&Bt[cl * 64 + ch * 8]);
      }
#pragma unroll
      for (int i = 0; i < 4; i++)
#pragma unroll
        for (int j = 0; j < 4; j++)
          acc[i][j] = __builtin_amdgcn_mfma_f32_16x16x32_bf16(af[i], bf[j], acc[i][j], 0, 0, 0);
    }
  }
  __syncthreads();
  float* fb = (float*)lds;
#pragma unroll
  for (int i = 0; i < 4; i++)
#pragma unroll
    for (int j = 0; j < 4; j++)
#pragma unroll
      for (int jj = 0; jj < 4; jj++) {
        const int row = wr * 64 + i * 16 + (l >> 4) * 4 + jj;
        const int col = wc * 64 + j * 16 + (l & 15);
        fb[row * 128 + col] = acc[i][j][jj];
      }
  __syncthreads();
#pragma unroll
  for (int kk = 0; kk < 16; kk++) {
    const int idx4 = kk * 256 + t;
    const int row = idx4 >> 5, c4 = idx4 & 31;
    *(float4*)(pvpart + ((size_t)bx * 4096 + r0 + row) * 128 + c4 * 4) = *(const float4*)&fb[row * 128 + c4 * 4];
  }
}

__global__ __launch_bounds__(256) void pvred_kernel(const float* __restrict__ pvpart,
    float* __restrict__ o2, float* __restrict__ o3) {
  const int idx4 = blockIdx.x * 256 + threadIdx.x;
  float4 s; s.x = s.y = s.z = s.w = 0.f;
#pragma unroll
  for (int ch = 0; ch < 8; ch++) {
    float4 p = *(const float4*)(pvpart + (size_t)ch * 524288 + (size_t)idx4 * 4);
    s.x += p.x; s.y += p.y; s.z += p.z; s.w += p.w;
  }
  *(float4*)(o2 + (size_t)idx4 * 4) = s;
  *(float4*)(o3 + (size_t)idx4 * 4) = s;
}

__global__ __launch_bounds__(256) void seedscatter_kernel(const int* __restrict__ topi,
    const float* __restrict__ topv, const int* __restrict__ invperm,
    float* __restrict__ out0) {
  const int b = blockIdx.x, t = threadIdx.x;
  int s = 0;
  for (int e = t; e < 640; e += 256) s += topi[b * 640 + e];
#pragma unroll
  for (int off = 32; off; off >>= 1) s += __shfl_xor(s, off);
  __shared__ int sred[4];
  if ((t & 63) == 0) sred[t >> 6] = s;
  __syncthreads();
  const int total = sred[0] + sred[1] + sred[2] + sred[3];
  const float avg = (float)total / 640.0f;
  const int sd = ((int)floorf(avg / 2048.0f)) & 3;
  const int* ip = invperm + sd * 8192;
  for (int e = t; e < 640; e += 256) {
    const int q = e / 40;
    const int i = topi[b * 640 + e];
    const float val = topv[b * 640 + e];
    out0[((size_t)(b * 16 + q)) * 8192 + ip[i]] = val;
  }
}

extern "C" void kernel_launch(void* const* d_in, const int* in_sizes, int n_in,
                              void* d_out, int out_size, void* d_ws, size_t ws_size,
                              hipStream_t stream) {
  const float* x   = (const float*)d_in[0];
  const float* emb = (const float*)d_in[1];
  const float* Wq  = (const float*)d_in[2];
  const float* bq  = (const float*)d_in[3];
  const float* Wv  = (const float*)d_in[4];
  const float* bv  = (const float*)d_in[5];
  const float* bng = (const float*)d_in[6];
  const float* bnb = (const float*)d_in[7];
  const float* lng = (const float*)d_in[8];
  const float* lnb = (const float*)d_in[9];

  float* out0  = (float*)d_out;          // attn_w_flat (also logits scratch)
  float* outq  = out0 + 33554432;        // q
  float* outap = outq + 524288;          // applied
  float* outaf = outap + 524288;         // applied_flat

  float* wsf    = (float*)d_ws;
  float* kbuf   = wsf;                     // 1048576
  float* vbuf   = kbuf + 1048576;          // 1048576
  float* qraw   = vbuf + 1048576;          // 524288
  float* bnpart = qraw + 524288;           // 8192
  float* bnstat = bnpart + 8192;           // 256
  float* rowmax = bnstat + 256;            // 4096
  float* rowsum = rowmax + 4096;           // 4096
  float* pvpart = rowsum + 4096;           // 8*524288 = 4194304
  float* topv   = pvpart + 4194304;        // 163840
  int*   topi    = (int*)(topv + 163840);  // 163840
  int*   invperm = topi + 163840;          // 32768
  unsigned short* qb = (unsigned short*)(invperm + 32768);  // 524288 ushort
  unsigned short* kT = qb + 524288;                         // 1048576 ushort
  unsigned short* vT = kT + 1048576;                        // 1048576 ushort

  perm_kernel<<<4, 1024, 65536, stream>>>(invperm);
  qraw_kernel<<<dim3(64, 4), 256, 0, stream>>>(x, Wq, bq, qraw);
  bnpart_kernel<<<32, 256, 0, stream>>>(qraw, bnpart);
  bnfin_kernel<<<1, 128, 0, stream>>>(bnpart, bng, bnb, bnstat);
  qnorm_kernel<<<512, 256, 0, stream>>>(qraw, bnstat, outq, qb);
  lnv_kernel<<<512, 256, 0, stream>>>(emb, Wv, bv, lng, lnb, kbuf, vbuf);
  ktrans_kernel<<<128, 256, 0, stream>>>(kbuf, kT);
  vtrans_kernel<<<128, 256, 0, stream>>>(vbuf, vT);
  gemm1_mfma<<<dim3(64, 32), 256, 0, stream>>>(qb, kT, out0);
  rowstat_topk_kernel<<<4096, 256, 0, stream>>>(out0, rowmax, rowsum, topv, topi);
  gemm2_mfma<<<dim3(8, 32), 256, 0, stream>>>(out0, vT, rowmax, rowsum, pvpart);
  pvred_kernel<<<512, 256, 0, stream>>>(pvpart, outap, outaf);
  hipMemsetAsync(d_out, 0, (size_t)33554432 * 4, stream);
  seedscatter_kernel<<<256, 256, 0, stream>>>(topi, topv, invperm, out0);
}

// Round 4
// 419.159 us; speedup vs baseline: 2.1609x; 1.4049x over previous
//
#include <hip/hip_runtime.h>
#include <hip/hip_bf16.h>
#include <stdint.h>

// N=8192, C1=512, C2=128, M=4, B=256, TOPK=40, R=B*M*M=4096
#define EPSF 1e-5f

typedef __bf16 b16x8 __attribute__((ext_vector_type(8)));
typedef float f32x4 __attribute__((ext_vector_type(4)));
typedef unsigned short u16x8 __attribute__((ext_vector_type(8)));

static __device__ __forceinline__ unsigned short f2bf(float f) {
  __hip_bfloat16 h = __float2bfloat16(f);
  return __builtin_bit_cast(unsigned short, h);
}

// ---------------- RNG (JAX threefry, partitionable) ----------------
__device__ __forceinline__ void threefry2x32(uint32_t k0, uint32_t k1,
                                             uint32_t c0, uint32_t c1,
                                             uint32_t& o0, uint32_t& o1) {
  const uint32_t ks2 = k0 ^ k1 ^ 0x1BD11BDAu;
  uint32_t x0 = c0 + k0, x1 = c1 + k1;
#define TFR(r) { x0 += x1; x1 = (x1 << (r)) | (x1 >> (32 - (r))); x1 ^= x0; }
  TFR(13) TFR(15) TFR(26) TFR(6)
  x0 += k1;  x1 += ks2 + 1u;
  TFR(17) TFR(29) TFR(16) TFR(24)
  x0 += ks2; x1 += k0 + 2u;
  TFR(13) TFR(15) TFR(26) TFR(6)
  x0 += k0;  x1 += k1 + 3u;
  TFR(17) TFR(29) TFR(16) TFR(24)
  x0 += k1;  x1 += ks2 + 4u;
  TFR(13) TFR(15) TFR(26) TFR(6)
  x0 += ks2; x1 += k0 + 5u;
#undef TFR
  o0 = x0; o1 = x1;
}

// rank-based permutation: invperm[s][v] = rank2[rank1[v]]
// rank_kernel computes rank of each element under stable sort by (bits, idx).
__global__ __launch_bounds__(256) void rank_kernel(int* __restrict__ rankbuf) {
  __shared__ uint32_t bits[8192];
  const int chunk = blockIdx.x;   // 0..31 (256 elements each)
  const int round = blockIdx.y;   // 0..1
  const int s     = blockIdx.z;   // 0..3
  const int t = threadIdx.x, l = t & 63, w = t >> 6;
  uint32_t ka, kb;
  {
    uint32_t k1a, k1b;
    threefry2x32(0u, (uint32_t)s, 0u, 0u, k1a, k1b);     // key1 = enc(0,0)
    if (round == 0) threefry2x32(0u, (uint32_t)s, 0u, 1u, ka, kb);   // subkey1
    else            threefry2x32(k1a, k1b, 0u, 1u, ka, kb);          // subkey2
  }
  for (int j = t; j < 8192; j += 256) {
    uint32_t t0, t1;
    threefry2x32(ka, kb, 0u, (uint32_t)j, t0, t1);
    bits[j] = t1;  // second output word (partitionable 32-bit draw)
  }
  __syncthreads();
  const int base = chunk * 256 + w * 64;  // wave's first element, 64-aligned
  const int i = base + l;
  const uint32_t myb = bits[i];
  const uint4* b4 = (const uint4*)bits;
  int rk = 0;
  // j < base: all lanes have j < i  ->  count b_j <= myb
  const int lo = base >> 2;
#pragma unroll 4
  for (int j4 = 0; j4 < lo; j4++) {
    const uint4 b = b4[j4];
    rk += (b.x <= myb) + (b.y <= myb) + (b.z <= myb) + (b.w <= myb);
  }
  // j in [base, base+64): mixed (lane boundary)
#pragma unroll
  for (int j4 = lo; j4 < lo + 16; j4++) {
    const uint4 b = b4[j4];
    const int j = j4 * 4;
    rk += (b.x < myb) + ((b.x == myb) && (j     < i));
    rk += (b.y < myb) + ((b.y == myb) && (j + 1 < i));
    rk += (b.z < myb) + ((b.z == myb) && (j + 2 < i));
    rk += (b.w < myb) + ((b.w == myb) && (j + 3 < i));
  }
  // j >= base+64: all lanes have j > i  ->  count b_j < myb
#pragma unroll 4
  for (int j4 = lo + 16; j4 < 2048; j4++) {
    const uint4 b = b4[j4];
    rk += (b.x < myb) + (b.y < myb) + (b.z < myb) + (b.w < myb);
  }
  rankbuf[(s * 2 + round) * 8192 + i] = rk;
}

__global__ __launch_bounds__(256) void compose_kernel(const int* __restrict__ rankbuf,
                                                      int* __restrict__ invperm) {
  const int s = blockIdx.y;
  const int v = blockIdx.x * 256 + threadIdx.x;
  const int* r1 = rankbuf + s * 16384;
  const int* r2 = r1 + 8192;
  invperm[s * 8192 + v] = r2[r1[v]];
}

// ---------------- q path ----------------
__global__ __launch_bounds__(256) void qraw_kernel(const float* __restrict__ x,
    const float* __restrict__ Wq, const float* __restrict__ bq,
    float* __restrict__ qraw) {
  __shared__ float ea[16][128];
  __shared__ float wq[128][132];
  const int t = threadIdx.x;
  const int g = blockIdx.x;
  const int m2 = blockIdx.y;
  for (int i = t; i < 512; i += 256) {
    float4 xx = *(const float4*)(x + (size_t)g * 2048 + i * 4);
    *(float4*)&ea[i >> 5][(i & 31) * 4] = xx;
  }
  for (int i = t; i < 4096; i += 256) {
    float4 ww = *(const float4*)(Wq + (size_t)m2 * 16384 + i * 4);
    *(float4*)&wq[i >> 5][(i & 31) * 4] = ww;
  }
  __syncthreads();
  const int row = t >> 4, j = t & 15;
  float acc[8] = {0.f,0.f,0.f,0.f,0.f,0.f,0.f,0.f};
  for (int d = 0; d < 128; d++) {
    const float xv = ea[row][d];
#pragma unroll
    for (int cc = 0; cc < 8; cc++) acc[cc] += xv * wq[j + cc * 16][d];
  }
  const int r = (g * 16 + row) * 4 + m2;
#pragma unroll
  for (int cc = 0; cc < 8; cc++) {
    const int c = j + cc * 16;
    qraw[(size_t)r * 128 + c] = acc[cc] + bq[m2 * 128 + c];
  }
}

__global__ __launch_bounds__(256) void bnpart_kernel(const float* __restrict__ qraw,
                                                     float* __restrict__ bnpart) {
  __shared__ float a1[256], a2[256];
  const int t = threadIdx.x, c = t & 127, h = t >> 7;
  float s1 = 0.f, s2 = 0.f;
  for (int i = 0; i < 64; i++) {
    float xv = qraw[(size_t)(blockIdx.x * 128 + h + 2 * i) * 128 + c];
    s1 += xv; s2 += xv * xv;
  }
  a1[t] = s1; a2[t] = s2;
  __syncthreads();
  if (t < 128) {
    bnpart[blockIdx.x * 256 + t]       = a1[t] + a1[t + 128];
    bnpart[blockIdx.x * 256 + 128 + t] = a2[t] + a2[t + 128];
  }
}

__global__ void bnfin_kernel(const float* __restrict__ bnpart,
                             const float* __restrict__ gamma,
                             const float* __restrict__ beta,
                             float* __restrict__ bnstat) {
  const int c = threadIdx.x;
  float s1 = 0.f, s2 = 0.f;
  for (int i = 0; i < 32; i++) { s1 += bnpart[i * 256 + c]; s2 += bnpart[i * 256 + 128 + c]; }
  const float mu  = s1 * (1.0f / 4096.0f);
  const float var = s2 * (1.0f / 4096.0f) - mu * mu;
  const float sc  = rsqrtf(var + EPSF) * gamma[c];
  bnstat[c]       = sc;
  bnstat[128 + c] = beta[c] - mu * sc;
}

__global__ __launch_bounds__(256) void qnorm_kernel(const float* __restrict__ qraw,
    const float* __restrict__ bnstat, float* __restrict__ outq,
    unsigned short* __restrict__ qb) {
  const int idx4 = blockIdx.x * 256 + threadIdx.x;
  float4 xv = *(const float4*)(qraw + (size_t)idx4 * 4);
  const int c0 = (idx4 * 4) & 127;
  float4 sc = *(const float4*)(bnstat + c0);
  float4 sh = *(const float4*)(bnstat + 128 + c0);
  float4 o;
  o.x = xv.x * sc.x + sh.x; o.y = xv.y * sc.y + sh.y;
  o.z = xv.z * sc.z + sh.z; o.w = xv.w * sc.w + sh.w;
  *(float4*)(outq + (size_t)idx4 * 4) = o;
  ushort4 ob;
  ob.x = f2bf(o.x); ob.y = f2bf(o.y); ob.z = f2bf(o.z); ob.w = f2bf(o.w);
  *(ushort4*)(qb + (size_t)idx4 * 4) = ob;
}

// ---------------- LN(emb) -> kbuf, emb@Wv^T+bv -> vbuf ----------------
__global__ __launch_bounds__(256) void lnv_kernel(const float* __restrict__ emb,
    const float* __restrict__ Wv, const float* __restrict__ bv,
    const float* __restrict__ lng, const float* __restrict__ lnb,
    float* __restrict__ kbuf, float* __restrict__ vbuf) {
  __shared__ float ea[16][128];
  __shared__ float wv[128][132];
  const int t = threadIdx.x;
  const int r0 = blockIdx.x * 16;
  for (int i = t; i < 512; i += 256) {
    float4 xx = *(const float4*)(emb + (size_t)r0 * 128 + i * 4);
    *(float4*)&ea[i >> 5][(i & 31) * 4] = xx;
  }
  for (int i = t; i < 4096; i += 256) {
    float4 ww = *(const float4*)(Wv + (size_t)i * 4);
    *(float4*)&wv[i >> 5][(i & 31) * 4] = ww;
  }
  __syncthreads();
  const int row = t >> 4, j = t & 15;
  float s1 = 0.f, s2 = 0.f;
#pragma unroll
  for (int m = 0; m < 8; m++) { float xv = ea[row][j + m * 16]; s1 += xv; s2 += xv * xv; }
#pragma unroll
  for (int off = 8; off; off >>= 1) {
    s1 += __shfl_xor(s1, off, 16);
    s2 += __shfl_xor(s2, off, 16);
  }
  const float mu   = s1 * 0.0078125f;
  const float var  = s2 * 0.0078125f - mu * mu;
  const float rstd = rsqrtf(var + EPSF);
#pragma unroll
  for (int m = 0; m < 8; m++) {
    const int d = j + m * 16;
    kbuf[(size_t)(r0 + row) * 128 + d] = (ea[row][d] - mu) * rstd * lng[d] + lnb[d];
  }
  float acc[8] = {0.f,0.f,0.f,0.f,0.f,0.f,0.f,0.f};
  for (int d = 0; d < 128; d++) {
    const float xv = ea[row][d];
#pragma unroll
    for (int cc = 0; cc < 8; cc++) acc[cc] += xv * wv[j + cc * 16][d];
  }
#pragma unroll
  for (int cc = 0; cc < 8; cc++) {
    const int c = j + cc * 16;
    vbuf[(size_t)(r0 + row) * 128 + c] = acc[cc] + bv[c];
  }
}

// ---------------- bf16 transposes for MFMA B-operands ----------------
__global__ __launch_bounds__(256) void ktrans_kernel(const float* __restrict__ kbuf,
                                                     unsigned short* __restrict__ kT) {
  __shared__ unsigned short s[64][136];
  const int b = blockIdx.x, t = threadIdx.x;
  const int k = t >> 1, half = t & 1;
  const float* src = kbuf + (size_t)(k * 64 + (b >> 1)) * 128 + (b & 1) * 64 + half * 32;
#pragma unroll
  for (int i = 0; i < 8; i++) {
    float4 v = *(const float4*)(src + i * 4);
    const int dn = half * 32 + i * 4;
    s[dn + 0][k] = f2bf(v.x); s[dn + 1][k] = f2bf(v.y);
    s[dn + 2][k] = f2bf(v.z); s[dn + 3][k] = f2bf(v.w);
  }
  __syncthreads();
  const int dn = t >> 2, q = t & 3;
  unsigned short* dst = kT + (size_t)(b * 64 + dn) * 128 + q * 32;
#pragma unroll
  for (int j = 0; j < 4; j++)
    *(int4*)(dst + j * 8) = *(const int4*)&s[dn][q * 32 + j * 8];
}

__global__ __launch_bounds__(256) void vtrans_kernel(const float* __restrict__ vbuf,
                                                     unsigned short* __restrict__ vT) {
  __shared__ unsigned short s[128][72];
  const int b = blockIdx.x, t = threadIdx.x;
  const int i0 = b * 64;
  const int di = t >> 2, q = t & 3;
  const float* src = vbuf + (size_t)(i0 + di) * 128 + q * 32;
#pragma unroll
  for (int i = 0; i < 8; i++) {
    float4 v = *(const float4*)(src + i * 4);
    const int c = q * 32 + i * 4;
    s[c + 0][di] = f2bf(v.x); s[c + 1][di] = f2bf(v.y);
    s[c + 2][di] = f2bf(v.z); s[c + 3][di] = f2bf(v.w);
  }
  __syncthreads();
  const int c = t >> 1, half = t & 1;
  unsigned short* dst = vT + (size_t)c * 8192 + i0 + half * 32;
#pragma unroll
  for (int j = 0; j < 4; j++)
    *(int4*)(dst + j * 8) = *(const int4*)&s[c][half * 32 + j * 8];
}

// ---------------- GEMM1 (MFMA): logits[4096][8192] = qb @ kT^T / sqrt(128) ----------------
__global__ __launch_bounds__(256) void gemm1_mfma(const unsigned short* __restrict__ qb,
    const unsigned short* __restrict__ kT, float* __restrict__ logits) {
  __shared__ __attribute__((aligned(16))) unsigned short lds[32768];  // 64KB
  unsigned short* At = lds;
  unsigned short* Bt = lds + 16384;
  const int t = threadIdx.x, l = t & 63, w = t >> 6;
  const int n0 = blockIdx.x * 128, r0 = blockIdx.y * 128;
  const int wr = w >> 1, wc = w & 1;
#pragma unroll
  for (int it = 0; it < 8; it++) {
    const int c = it * 256 + t;
    const int row = c >> 4, ch = c & 15;
    const int chs = ch ^ (row & 7);
    const unsigned short* gA = qb + (size_t)(r0 + row) * 128 + chs * 8;
    const unsigned short* gB = kT + (size_t)(n0 + row) * 128 + chs * 8;
    __builtin_amdgcn_global_load_lds((const __attribute__((address_space(1))) void*)gA,
        (__attribute__((address_space(3))) void*)(At + (size_t)(it * 256 + w * 64) * 8), 16, 0, 0);
    __builtin_amdgcn_global_load_lds((const __attribute__((address_space(1))) void*)gB,
        (__attribute__((address_space(3))) void*)(Bt + (size_t)(it * 256 + w * 64) * 8), 16, 0, 0);
  }
  __syncthreads();
  f32x4 acc[4][4];
#pragma unroll
  for (int i = 0; i < 4; i++)
#pragma unroll
    for (int j = 0; j < 4; j++) acc[i][j] = (f32x4){0.f, 0.f, 0.f, 0.f};
#pragma unroll
  for (int ks = 0; ks < 4; ks++) {
    b16x8 af[4], bf[4];
#pragma unroll
    for (int i = 0; i < 4; i++) {
      const int rl = wr * 64 + i * 16 + (l & 15);
      const int ch = (ks * 4 + (l >> 4)) ^ (rl & 7);
      af[i] = __builtin_bit_cast(b16x8, *(const u16x8*)&At[rl * 128 + ch * 8]);
    }
#pragma unroll
    for (int j = 0; j < 4; j++) {
      const int cl = wc * 64 + j * 16 + (l & 15);
      const int ch = (ks * 4 + (l >> 4)) ^ (cl & 7);
      bf[j] = __builtin_bit_cast(b16x8, *(const u16x8*)&Bt[cl * 128 + ch * 8]);
    }
#pragma unroll
    for (int i = 0; i < 4; i++)
#pragma unroll
      for (int j = 0; j < 4; j++)
        acc[i][j] = __builtin_amdgcn_mfma_f32_16x16x32_bf16(af[i], bf[j], acc[i][j], 0, 0, 0);
  }
  __syncthreads();
  float* fb = (float*)lds;
  const float rs = 0.08838834764831845f;
#pragma unroll
  for (int i = 0; i < 4; i++)
#pragma unroll
    for (int j = 0; j < 4; j++) {
#pragma unroll
      for (int jj = 0; jj < 4; jj++) {
        const int row = wr * 64 + i * 16 + (l >> 4) * 4 + jj;
        const int col = wc * 64 + j * 16 + (l & 15);
        fb[row * 128 + col] = acc[i][j][jj] * rs;
      }
    }
  __syncthreads();
#pragma unroll
  for (int kk = 0; kk < 16; kk++) {
    const int idx4 = kk * 256 + t;
    const int row = idx4 >> 5, c4 = idx4 & 31;
    *(float4*)(logits + (size_t)(r0 + row) * 8192 + n0 + c4 * 4) = *(const float4*)&fb[row * 128 + c4 * 4];
  }
}

// ---------------- row stats + top-40 via threshold-select + rank ----------------
__global__ __launch_bounds__(256) void rowstat_topk_kernel(const float* __restrict__ logits,
    float* __restrict__ rowmax, float* __restrict__ rowsum,
    float* __restrict__ topv, int* __restrict__ topi) {
  const int r = blockIdx.x, t = threadIdx.x;
  const int l = t & 63, w = t >> 6;
  const float* row = logits + (size_t)r * 8192;
  float4 v[8];
#pragma unroll
  for (int m = 0; m < 8; m++) v[m] = *(const float4*)(row + m * 1024 + t * 4);

  __shared__ float sredf[4];
  __shared__ int scnt[16];
  __shared__ unsigned long long keys[1024];
  __shared__ int lcnt;

  float bm = -3.0e38f;
#pragma unroll
  for (int m = 0; m < 8; m++)
    bm = fmaxf(bm, fmaxf(fmaxf(v[m].x, v[m].y), fmaxf(v[m].z, v[m].w)));
#pragma unroll
  for (int off = 32; off; off >>= 1) bm = fmaxf(bm, __shfl_xor(bm, off));
  if (l == 0) sredf[w] = bm;
  __syncthreads();
  const float gmax = fmaxf(fmaxf(sredf[0], sredf[1]), fmaxf(sredf[2], sredf[3]));

  float ls = 0.f;
#pragma unroll
  for (int m = 0; m < 8; m++)
    ls += expf(v[m].x - gmax) + expf(v[m].y - gmax) + expf(v[m].z - gmax) + expf(v[m].w - gmax);
#pragma unroll
  for (int off = 32; off; off >>= 1) ls += __shfl_xor(ls, off);
  __syncthreads();
  if (l == 0) sredf[w] = ls;
  __syncthreads();
  const float gsum = sredf[0] + sredf[1] + sredf[2] + sredf[3];
  if (t == 0) { rowmax[r] = gmax; rowsum[r] = gsum; }

  float theta = -3.0e38f;
  bool found = false;
  for (int trial = 0; trial < 8 && !found; trial++) {
    const float base = gmax - 8.0f * (float)trial;
    int c[16];
#pragma unroll
    for (int j = 0; j < 16; j++) c[j] = 0;
#pragma unroll
    for (int m = 0; m < 8; m++) {
#pragma unroll
      for (int j = 0; j < 16; j++) {
        const float th = base - 0.5f * (float)(j + 1);
        c[j] += (v[m].x >= th) + (v[m].y >= th) + (v[m].z >= th) + (v[m].w >= th);
      }
    }
#pragma unroll
    for (int j = 0; j < 16; j++) {
#pragma unroll
      for (int off = 32; off; off >>= 1) c[j] += __shfl_xor(c[j], off);
    }
    if (t < 16) scnt[t] = 0;
    __syncthreads();
    if (l == 0) {
#pragma unroll
      for (int j = 0; j < 16; j++) atomicAdd(&scnt[j], c[j]);
    }
    __syncthreads();
    for (int j = 0; j < 16; j++) {
      if (scnt[j] >= 40) { theta = base - 0.5f * (float)(j + 1); found = true; break; }
    }
    __syncthreads();
  }

  if (t == 0) lcnt = 0;
  __syncthreads();
#pragma unroll
  for (int m = 0; m < 8; m++) {
    const int gb = m * 1024 + t * 4;
    const float vals[4] = {v[m].x, v[m].y, v[m].z, v[m].w};
#pragma unroll
    for (int e = 0; e < 4; e++) {
      if (vals[e] >= theta) {
        const int pos = atomicAdd(&lcnt, 1);
        if (pos < 1024) {
          const uint32_t s = __float_as_uint(vals[e]);
          const uint32_t mkey = (s & 0x80000000u) ? ~s : (s | 0x80000000u);
          keys[pos] = ((unsigned long long)(~mkey) << 32) | (unsigned)(gb + e);
        }
      }
    }
  }
  __syncthreads();
  const int cnt = min(lcnt, 1024);
  const float rgs = 1.0f / gsum;
  for (int i = t; i < cnt; i += 256) {
    const unsigned long long K = keys[i];
    int rank = 0;
#pragma unroll 4
    for (int p = 0; p < cnt; p++) rank += (keys[p] < K) ? 1 : 0;
    if (rank < 40) {
      const uint32_t desc = (uint32_t)(K >> 32);
      const uint32_t mkey = ~desc;
      const uint32_t sb = (mkey & 0x80000000u) ? (mkey & 0x7FFFFFFFu) : ~mkey;
      const float val = __uint_as_float(sb);
      topi[r * 40 + rank] = (int)(K & 0xFFFFFFFFu);
      topv[r * 40 + rank] = expf(val - gmax) * rgs;
    }
  }
}

// ---------------- GEMM2 (MFMA): pvpart[chunk][4096][128] = softmax(logits) @ V ----------------
__global__ __launch_bounds__(256) void gemm2_mfma(const float* __restrict__ logits,
    const unsigned short* __restrict__ vT, const float* __restrict__ rowmax,
    const float* __restrict__ rowsum, float* __restrict__ pvpart) {
  __shared__ __attribute__((aligned(16))) unsigned short lds[32768];  // 64KB
  unsigned short* At = lds;
  unsigned short* Bt = lds + 8192;
  const int t = threadIdx.x, l = t & 63, w = t >> 6;
  const int bx = blockIdx.x;
  const int by = blockIdx.y;
  const int r0 = by * 128;
  const int kb0 = bx * 1024;
  const int wr = w >> 1, wc = w & 1;
  const int prow = t >> 1, pk = (t & 1) * 32;
  const float rm = rowmax[r0 + prow];
  const float ri = 1.0f / rowsum[r0 + prow];

  f32x4 acc[4][4];
#pragma unroll
  for (int i = 0; i < 4; i++)
#pragma unroll
    for (int j = 0; j < 4; j++) acc[i][j] = (f32x4){0.f, 0.f, 0.f, 0.f};

  for (int ks = 0; ks < 16; ks++) {
    const int k0 = kb0 + ks * 64;
    __syncthreads();
#pragma unroll
    for (int it = 0; it < 4; it++) {
      const int c = it * 256 + t;
      const int rowc = c >> 3, ch = c & 7;
      const int chs = ch ^ (rowc & 7);
      const unsigned short* gB = vT + (size_t)rowc * 8192 + k0 + chs * 8;
      __builtin_amdgcn_global_load_lds((const __attribute__((address_space(1))) void*)gB,
          (__attribute__((address_space(3))) void*)(Bt + (size_t)(it * 256 + w * 64) * 8), 16, 0, 0);
    }
    const float* lsrc = logits + (size_t)(r0 + prow) * 8192 + k0 + pk;
#pragma unroll
    for (int c8 = 0; c8 < 4; c8++) {
      float4 v0 = *(const float4*)(lsrc + c8 * 8);
      float4 v1 = *(const float4*)(lsrc + c8 * 8 + 4);
      u16x8 pkd;
      pkd[0] = f2bf(expf(v0.x - rm) * ri); pkd[1] = f2bf(expf(v0.y - rm) * ri);
      pkd[2] = f2bf(expf(v0.z - rm) * ri); pkd[3] = f2bf(expf(v0.w - rm) * ri);
      pkd[4] = f2bf(expf(v1.x - rm) * ri); pkd[5] = f2bf(expf(v1.y - rm) * ri);
      pkd[6] = f2bf(expf(v1.z - rm) * ri); pkd[7] = f2bf(expf(v1.w - rm) * ri);
      const int chunkidx = (t & 1) * 4 + c8;
      const int phys = chunkidx ^ (prow & 7);
      *(u16x8*)&At[prow * 64 + phys * 8] = pkd;
    }
    __syncthreads();
#pragma unroll
    for (int s = 0; s < 2; s++) {
      b16x8 af[4], bf[4];
#pragma unroll
      for (int i = 0; i < 4; i++) {
        const int rl = wr * 64 + i * 16 + (l & 15);
        const int ch = (s * 4 + (l >> 4)) ^ (rl & 7);
        af[i] = __builtin_bit_cast(b16x8, *(const u16x8*)&At[rl * 64 + ch * 8]);
      }
#pragma unroll
      for (int j = 0; j < 4; j++) {
        const int cl = wc * 64 + j * 16 + (l & 15);
        const int ch = (s * 4 + (l >> 4)) ^ (cl & 7);
        bf[j] = __builtin_bit_cast(b16x8, *(const u16x8*)&Bt[cl * 64 + ch * 8]);
      }
#pragma unroll
      for (int i = 0; i < 4; i++)
#pragma unroll
        for (int j = 0; j < 4; j++)
          acc[i][j] = __builtin_amdgcn_mfma_f32_16x16x32_bf16(af[i], bf[j], acc[i][j], 0, 0, 0);
    }
  }
  __syncthreads();
  float* fb = (float*)lds;
#pragma unroll
  for (int i = 0; i < 4; i++)
#pragma unroll
    for (int j = 0; j < 4; j++)
#pragma unroll
      for (int jj = 0; jj < 4; jj++) {
        const int row = wr * 64 + i * 16 + (l >> 4) * 4 + jj;
        const int col = wc * 64 + j * 16 + (l & 15);
        fb[row * 128 + col] = acc[i][j][jj];
      }
  __syncthreads();
#pragma unroll
  for (int kk = 0; kk < 16; kk++) {
    const int idx4 = kk * 256 + t;
    const int row = idx4 >> 5, c4 = idx4 & 31;
    *(float4*)(pvpart + ((size_t)bx * 4096 + r0 + row) * 128 + c4 * 4) = *(const float4*)&fb[row * 128 + c4 * 4];
  }
}

__global__ __launch_bounds__(256) void pvred_kernel(const float* __restrict__ pvpart,
    float* __restrict__ o2, float* __restrict__ o3) {
  const int idx4 = blockIdx.x * 256 + threadIdx.x;
  float4 s; s.x = s.y = s.z = s.w = 0.f;
#pragma unroll
  for (int ch = 0; ch < 8; ch++) {
    float4 p = *(const float4*)(pvpart + (size_t)ch * 524288 + (size_t)idx4 * 4);
    s.x += p.x; s.y += p.y; s.z += p.z; s.w += p.w;
  }
  *(float4*)(o2 + (size_t)idx4 * 4) = s;
  *(float4*)(o3 + (size_t)idx4 * 4) = s;
}

__global__ __launch_bounds__(256) void seedscatter_kernel(const int* __restrict__ topi,
    const float* __restrict__ topv, const int* __restrict__ invperm,
    float* __restrict__ out0) {
  const int b = blockIdx.x, t = threadIdx.x;
  int s = 0;
  for (int e = t; e < 640; e += 256) s += topi[b * 640 + e];
#pragma unroll
  for (int off = 32; off; off >>= 1) s += __shfl_xor(s, off);
  __shared__ int sred[4];
  if ((t & 63) == 0) sred[t >> 6] = s;
  __syncthreads();
  const int total = sred[0] + sred[1] + sred[2] + sred[3];
  const float avg = (float)total / 640.0f;
  const int sd = ((int)floorf(avg / 2048.0f)) & 3;
  const int* ip = invperm + sd * 8192;
  for (int e = t; e < 640; e += 256) {
    const int q = e / 40;
    const int i = topi[b * 640 + e];
    const float val = topv[b * 640 + e];
    out0[((size_t)(b * 16 + q)) * 8192 + ip[i]] = val;
  }
}

extern "C" void kernel_launch(void* const* d_in, const int* in_sizes, int n_in,
                              void* d_out, int out_size, void* d_ws, size_t ws_size,
                              hipStream_t stream) {
  const float* x   = (const float*)d_in[0];
  const float* emb = (const float*)d_in[1];
  const float* Wq  = (const float*)d_in[2];
  const float* bq  = (const float*)d_in[3];
  const float* Wv  = (const float*)d_in[4];
  const float* bv  = (const float*)d_in[5];
  const float* bng = (const float*)d_in[6];
  const float* bnb = (const float*)d_in[7];
  const float* lng = (const float*)d_in[8];
  const float* lnb = (const float*)d_in[9];

  float* out0  = (float*)d_out;          // attn_w_flat (also logits scratch)
  float* outq  = out0 + 33554432;        // q
  float* outap = outq + 524288;          // applied
  float* outaf = outap + 524288;         // applied_flat

  float* wsf    = (float*)d_ws;
  float* kbuf   = wsf;                     // 1048576
  float* vbuf   = kbuf + 1048576;          // 1048576
  float* qraw   = vbuf + 1048576;          // 524288
  float* bnpart = qraw + 524288;           // 8192
  float* bnstat = bnpart + 8192;           // 256
  float* rowmax = bnstat + 256;            // 4096
  float* rowsum = rowmax + 4096;           // 4096
  float* pvpart = rowsum + 4096;           // 8*524288 = 4194304
  float* topv   = pvpart + 4194304;        // 163840
  int*   topi    = (int*)(topv + 163840);  // 163840
  int*   invperm = topi + 163840;          // 32768
  int*   rankbuf = invperm + 32768;        // 65536 (4 seeds x 2 rounds x 8192)
  unsigned short* qb = (unsigned short*)(rankbuf + 65536);  // 524288 ushort
  unsigned short* kT = qb + 524288;                         // 1048576 ushort
  unsigned short* vT = kT + 1048576;                        // 1048576 ushort

  rank_kernel<<<dim3(32, 2, 4), 256, 0, stream>>>(rankbuf);
  compose_kernel<<<dim3(32, 4), 256, 0, stream>>>(rankbuf, invperm);
  qraw_kernel<<<dim3(64, 4), 256, 0, stream>>>(x, Wq, bq, qraw);
  bnpart_kernel<<<32, 256, 0, stream>>>(qraw, bnpart);
  bnfin_kernel<<<1, 128, 0, stream>>>(bnpart, bng, bnb, bnstat);
  qnorm_kernel<<<512, 256, 0, stream>>>(qraw, bnstat, outq, qb);
  lnv_kernel<<<512, 256, 0, stream>>>(emb, Wv, bv, lng, lnb, kbuf, vbuf);
  ktrans_kernel<<<128, 256, 0, stream>>>(kbuf, kT);
  vtrans_kernel<<<128, 256, 0, stream>>>(vbuf, vT);
  gemm1_mfma<<<dim3(64, 32), 256, 0, stream>>>(qb, kT, out0);
  rowstat_topk_kernel<<<4096, 256, 0, stream>>>(out0, rowmax, rowsum, topv, topi);
  gemm2_mfma<<<dim3(8, 32), 256, 0, stream>>>(out0, vT, rowmax, rowsum, pvpart);
  pvred_kernel<<<512, 256, 0, stream>>>(pvpart, outap, outaf);
  hipMemsetAsync(d_out, 0, (size_t)33554432 * 4, stream);
  seedscatter_kernel<<<256, 256, 0, stream>>>(topi, topv, invperm, out0);
}